// Round 3
// baseline (619.742 us; speedup 1.0000x reference)
//
#include <hip/hip_runtime.h>
#include <hip/hip_bf16.h>
#include <vector>
#include <algorithm>
#include <utility>
#include <stdint.h>

// Problem constants
#define BB 2
#define PP 4096        // H*W
#define FF 288         // C*9
#define KK 32
#define NBASE 32
#define HID 64
#define COUT 64
#define NWG_KM 32      // k-means workgroups (16 per batch)
#define SUBS 16
#define OUT_ELEMS 524288   // 2*64*4096; idx chunk follows

// Set to 0 if idx turns out wrong => legacy (non-partitionable) threefry mode
#define THREEFRY_PARTITIONABLE 1

typedef unsigned short u16;

// ---------------- ws layout (bytes), total ~330 KB ----------------
// [0..63] barrier (memset 0), [64..67] dtype flag (written by kDetect)
#define OFF_IDX   512          // 2*4096*4  = 32768
#define OFF_ATTN  33280        // 64*32*4   = 8192
#define OFF_BIAS  41472        // 64*64*4   = 16384
#define OFF_PART  57856        // 64*1056*4 = 270336  -> ends 328192

struct InitIdx { int v[2][32]; };

// ---------------- device helpers ----------------
__device__ __forceinline__ float bf2f(u16 u){
  union { unsigned int i; float f; } cv; cv.i = ((unsigned int)u) << 16; return cv.f;
}
__device__ __forceinline__ u16 f2bf(float f){
  union { float f; unsigned int i; } cv; cv.f = f;
  unsigned int x = cv.i;
  unsigned int r = (x + 0x7FFFu + ((x >> 16) & 1u)) >> 16;
  return (u16)r;
}

template<bool BF>
__device__ __forceinline__ float ld(const void* p, size_t i){
  if constexpr (BF) { return bf2f(((const u16*)p)[i]); }
  else              { return ((const float*)p)[i]; }
}
template<bool BF>
__device__ __forceinline__ void st(void* p, size_t i, float v){
  if constexpr (BF) { ((u16*)p)[i] = f2bf(v); }
  else              { ((float*)p)[i] = v; }
}

// 3x3 box mean of one channel plane at (h,w), zero-padded borders. bi = element index of plane start.
template<bool BF>
__device__ __forceinline__ float obs_chan(const void* x, size_t bi, int h, int w){
  float s = 0.f;
  #pragma unroll
  for (int dh=-1; dh<=1; ++dh){
    int hh = h + dh;
    #pragma unroll
    for (int dw=-1; dw<=1; ++dw){
      int ww = w + dw;
      float v = 0.f;
      if ((unsigned)hh < 64u && (unsigned)ww < 64u) v = ld<BF>(x, bi + (hh<<6) + ww);
      s += v;
    }
  }
  return s / 9.0f;
}

__device__ __forceinline__ void gbar(int* cnt, int* gen, int nwg){
  __threadfence();
  __syncthreads();
  if (threadIdx.x == 0){
    int g = __hip_atomic_load(gen, __ATOMIC_RELAXED, __HIP_MEMORY_SCOPE_AGENT);
    int prev = __hip_atomic_fetch_add(cnt, 1, __ATOMIC_ACQ_REL, __HIP_MEMORY_SCOPE_AGENT);
    if (prev == nwg - 1){
      __hip_atomic_store(cnt, 0, __ATOMIC_RELAXED, __HIP_MEMORY_SCOPE_AGENT);
      __hip_atomic_fetch_add(gen, 1, __ATOMIC_RELEASE, __HIP_MEMORY_SCOPE_AGENT);
    } else {
      while (__hip_atomic_load(gen, __ATOMIC_ACQUIRE, __HIP_MEMORY_SCOPE_AGENT) == g){
        __builtin_amdgcn_s_sleep(8);
      }
    }
  }
  __syncthreads();
  __threadfence();
}

// ---------------- Kernel 0: input dtype detection ----------------
// Even u16 slots of a bf16 tensor are real bf16 values (|v|<16 for N(0,1) data).
// Even u16 slots of an f32 tensor are f32 LOW halves: pseudo-random exponents,
// ~49% have exp>=131 (|v|>=16 or inf/nan). Count "bad" among 1024 probes.
__global__ __launch_bounds__(256) void kDetect(const void* __restrict__ x, int* flag){
  __shared__ int cnt;
  if (threadIdx.x == 0) cnt = 0;
  __syncthreads();
  const u16* p = (const u16*)x;
  int bad = 0;
  for (int i = threadIdx.x; i < 1024; i += 256){
    u16 u = p[2*i];
    unsigned e = (u >> 7) & 0xFFu;
    if (e >= 131u) ++bad;
  }
  atomicAdd(&cnt, bad);
  __syncthreads();
  if (threadIdx.x == 0) *flag = (cnt < 102) ? 1 : 0;   // <10% bad => bf16
}

// ---------------- Kernel B body: persistent k-means ----------------
template<bool BF>
__device__ void kB_body(const void* __restrict__ x,
                        float* __restrict__ part,
                        int* __restrict__ idxg,
                        void* __restrict__ dout,
                        int* __restrict__ bar,
                        const InitIdx& ii){
  const int t   = threadIdx.x;
  const int wg  = blockIdx.x;
  const int mb  = wg >> 4;        // batch
  const int sub = wg & 15;
  const int pg  = sub*256 + t;    // point within batch

  __shared__ float obs_st[256][33];
  __shared__ float cent[2][32][32];
  __shared__ float cc_s[32];
  __shared__ int   a_loc[256];
  __shared__ float sq[32][32];
  __shared__ float snorm[32];
  __shared__ float cntsh[32];

  float o[32];
  {
    int h = pg >> 6, w = pg & 63;
    size_t xb = (size_t)mb << 17;
    for (int c=0; c<32; ++c){
      float v = obs_chan<BF>(x, xb + ((size_t)c<<12), h, w);
      o[c] = v; obs_st[t][c] = v;
    }
  }
  if (t < 64){
    int bb = t >> 5, j = t & 31;
    int q = ii.v[bb][j];
    int qh = q >> 6, qw = q & 63;
    size_t xq = (size_t)bb << 17;
    for (int c=0; c<32; ++c) cent[bb][j][c] = obs_chan<BF>(x, xq + ((size_t)c<<12), qh, qw);
  }
  __syncthreads();

  float ss = 0.f;
  #pragma unroll
  for (int d=0; d<32; ++d) ss = fmaf(o[d], o[d], ss);

  bool act0 = true, act1 = true;
  int parity = 0;

  for (int it=0; it<20; ++it){
    if (!(act0 || act1)) break;
    bool mine = (mb==0) ? act0 : act1;
    if (mine){
      if (t < 32){
        float s = 0.f;
        #pragma unroll
        for (int d=0; d<32; ++d){ float v = cent[mb][t][d]; s = fmaf(v,v,s); }
        cc_s[t] = s;
      }
      __syncthreads();
      float best = 3.0e38f; int bk = 0;
      for (int k=0; k<32; ++k){
        const float* cr = &cent[mb][k][0];
        float dot = 0.f;
        #pragma unroll
        for (int d=0; d<32; ++d) dot = fmaf(o[d], cr[d], dot);
        float dist = (ss - 2.0f*dot) + cc_s[k];
        if (dist < best){ best = dist; bk = k; }
      }
      a_loc[t] = bk;
      __syncthreads();
      const int d = t & 31, g = t >> 5;
      float s0=0.f, s1=0.f, s2=0.f, s3=0.f;
      #pragma unroll 4
      for (int p=0; p<256; ++p){
        int ap = a_loc[p];
        float v = obs_st[p][d];
        s0 += (ap==g     ) ? v : 0.f;
        s1 += (ap==g + 8 ) ? v : 0.f;
        s2 += (ap==g + 16) ? v : 0.f;
        s3 += (ap==g + 24) ? v : 0.f;
      }
      float* Pg = part + ((size_t)((parity*2 + mb)*SUBS + sub))*1056;
      __hip_atomic_store(Pg + (g    )*33 + d, s0, __ATOMIC_RELAXED, __HIP_MEMORY_SCOPE_AGENT);
      __hip_atomic_store(Pg + (g+ 8 )*33 + d, s1, __ATOMIC_RELAXED, __HIP_MEMORY_SCOPE_AGENT);
      __hip_atomic_store(Pg + (g+16 )*33 + d, s2, __ATOMIC_RELAXED, __HIP_MEMORY_SCOPE_AGENT);
      __hip_atomic_store(Pg + (g+24 )*33 + d, s3, __ATOMIC_RELAXED, __HIP_MEMORY_SCOPE_AGENT);
      if (t < 32){
        int cnt_ = 0;
        #pragma unroll 4
        for (int p=0; p<256; ++p) cnt_ += (a_loc[p] == t) ? 1 : 0;
        __hip_atomic_store(Pg + t*33 + 32, (float)cnt_, __ATOMIC_RELAXED, __HIP_MEMORY_SCOPE_AGENT);
      }
    }
    gbar(bar, bar+1, NWG_KM);
    for (int bb=0; bb<2; ++bb){
      bool ab = (bb==0) ? act0 : act1;
      if (!ab) continue;
      const float* Pb = part + ((size_t)((parity*2 + bb)*SUBS))*1056;
      if (t < 32){
        float s = 0.f;
        for (int si=0; si<SUBS; ++si)
          s += __hip_atomic_load(Pb + (size_t)si*1056 + t*33 + 32, __ATOMIC_RELAXED, __HIP_MEMORY_SCOPE_AGENT);
        cntsh[t] = s;
      }
      __syncthreads();
      for (int e=t; e<1024; e+=256){
        int k = e >> 5, d = e & 31;
        float s = 0.f;
        for (int si=0; si<SUBS; ++si)
          s += __hip_atomic_load(Pb + (size_t)si*1056 + k*33 + d, __ATOMIC_RELAXED, __HIP_MEMORY_SCOPE_AGENT);
        float oldv = cent[bb][k][d];
        float cn = cntsh[k];
        float nv = (cn > 0.f) ? (s / fmaxf(cn, 1.f)) : oldv;
        float dd = nv - oldv;
        sq[k][d] = dd*dd;
        cent[bb][k][d] = nv;
      }
      __syncthreads();
      if (t < 32){
        float s = 0.f;
        #pragma unroll
        for (int d=0; d<32; ++d) s += sq[t][d];
        snorm[t] = sqrtf(s);
      }
      __syncthreads();
      float sh = 0.f;
      for (int k=0;k<32;++k) sh += snorm[k];
      bool na = ((it+1) < 20) && ((double)sh >= 20.48);   // TOL*n, np promote-to-f64 semantics
      if (bb==0) act0 = na; else act1 = na;
      __syncthreads();
    }
    parity ^= 1;
  }
  __syncthreads();
  if (t < 32){
    float s = 0.f;
    #pragma unroll
    for (int d=0; d<32; ++d){ float v = cent[mb][t][d]; s = fmaf(v,v,s); }
    cc_s[t] = s;
  }
  __syncthreads();
  float best = 3.0e38f; int bk = 0;
  for (int k=0; k<32; ++k){
    const float* cr = &cent[mb][k][0];
    float dot = 0.f;
    #pragma unroll
    for (int d=0; d<32; ++d) dot = fmaf(o[d], cr[d], dot);
    float dist = (ss - 2.0f*dot) + cc_s[k];
    if (dist < best){ best = dist; bk = k; }
  }
  idxg[mb*PP + pg] = bk;
  st<BF>(dout, (size_t)OUT_ELEMS + mb*PP + pg, (float)bk);
}

__global__ __launch_bounds__(256) void kB(const void* x, float* part, int* idxg,
                                          void* dout, int* bar, const int* flag, InitIdx ii){
  if (*flag) kB_body<true >(x, part, idxg, dout, bar, ii);
  else       kB_body<false>(x, part, idxg, dout, bar, ii);
}

// ---------------- Kernel CD body: cluster patch-means + 2 MLPs + softmax ----------
template<bool BF>
__device__ void kCD_body(const void* __restrict__ x,
                         const int* __restrict__ idxg,
                         const void* kg_w1, const void* kg_b1,
                         const void* kg_w2, const void* kg_b2,
                         const void* kg_w3, const void* kg_b3,
                         const void* bg_w1, const void* bg_b1,
                         const void* bg_w2, const void* bg_b2,
                         const void* bg_w3, const void* bg_b3,
                         float* __restrict__ attn,
                         float* __restrict__ biasO){
  int wg = blockIdx.x; int b = wg >> 5; int k = wg & 31;
  int t = threadIdx.x;
  __shared__ int   idxsh[4096];
  __shared__ float row[FF];
  __shared__ float h1[64];
  __shared__ float h2[64];
  __shared__ float lgs[32];

  for (int e=t; e<4096; e+=256) idxsh[e] = idxg[b*PP + e];
  __syncthreads();

  int f1 = t;
  int c1 = f1 / 9, j1 = f1 % 9;
  int dh1 = j1/3 - 1, dw1 = j1%3 - 1;
  size_t x1 = ((size_t)b << 17) + ((size_t)c1 << 12);
  int f2 = 256 + t;
  int c2 = f2 / 9, j2 = f2 % 9;
  int dh2 = j2/3 - 1, dw2 = j2%3 - 1;
  size_t x2 = ((size_t)b << 17) + ((size_t)c2 << 12);

  float s1 = 0.f, s2 = 0.f; int cl = 0;
  for (int p=0; p<4096; ++p){
    if (idxsh[p] == k){
      ++cl;
      int h = p >> 6, w = p & 63;
      int hh = h + dh1, ww = w + dw1;
      if ((unsigned)hh < 64u && (unsigned)ww < 64u) s1 += ld<BF>(x, x1 + (hh<<6) + ww);
      if (t < 32){
        int hh2 = h + dh2, ww2 = w + dw2;
        if ((unsigned)hh2 < 64u && (unsigned)ww2 < 64u) s2 += ld<BF>(x, x2 + (hh2<<6) + ww2);
      }
    }
  }
  float den = fmaxf((float)cl, 1.f);
  row[f1] = s1 / den;
  if (t < 32) row[f2] = s2 / den;
  __syncthreads();

  if (t < 64){
    float s = 0.f;
    #pragma unroll 8
    for (int f=0; f<FF; ++f) s = fmaf(row[f], ld<BF>(kg_w1, f*HID + t), s);
    h1[t] = fmaxf(s + ld<BF>(kg_b1, t), 0.f);
  }
  __syncthreads();
  if (t < 64){
    float s = 0.f;
    #pragma unroll 8
    for (int h=0; h<HID; ++h) s = fmaf(h1[h], ld<BF>(kg_w2, h*HID + t), s);
    h2[t] = fmaxf(s + ld<BF>(kg_b2, t), 0.f);
  }
  __syncthreads();
  if (t < 32){
    float s = 0.f;
    #pragma unroll 8
    for (int h=0; h<HID; ++h) s = fmaf(h2[h], ld<BF>(kg_w3, h*NBASE + t), s);
    lgs[t] = s + ld<BF>(kg_b3, t);
  }
  __syncthreads();
  if (t < 32){
    float mx = -3.0e38f;
    for (int i=0;i<NBASE;++i) mx = fmaxf(mx, lgs[i]);
    float se = 0.f;
    for (int i=0;i<NBASE;++i) se += expf(lgs[i]-mx);
    attn[wg*NBASE + t] = expf(lgs[t]-mx) / se;
  }
  __syncthreads();
  if (t < 64){
    float s = 0.f;
    #pragma unroll 8
    for (int f=0; f<FF; ++f) s = fmaf(row[f], ld<BF>(bg_w1, f*HID + t), s);
    h1[t] = fmaxf(s + ld<BF>(bg_b1, t), 0.f);
  }
  __syncthreads();
  if (t < 64){
    float s = 0.f;
    #pragma unroll 8
    for (int h=0; h<HID; ++h) s = fmaf(h1[h], ld<BF>(bg_w2, h*HID + t), s);
    h2[t] = fmaxf(s + ld<BF>(bg_b2, t), 0.f);
  }
  __syncthreads();
  if (t < 64){
    float s = 0.f;
    #pragma unroll 8
    for (int h=0; h<HID; ++h) s = fmaf(h2[h], ld<BF>(bg_w3, h*COUT + t), s);
    biasO[wg*COUT + t] = s + ld<BF>(bg_b3, t);
  }
}

__global__ __launch_bounds__(256) void kCD(const void* x, const int* idxg,
                                           const void* kg_w1, const void* kg_b1,
                                           const void* kg_w2, const void* kg_b2,
                                           const void* kg_w3, const void* kg_b3,
                                           const void* bg_w1, const void* bg_b1,
                                           const void* bg_w2, const void* bg_b2,
                                           const void* bg_w3, const void* bg_b3,
                                           float* attn, float* biasO, const int* flag){
  if (*flag) kCD_body<true >(x, idxg, kg_w1,kg_b1,kg_w2,kg_b2,kg_w3,kg_b3,
                             bg_w1,bg_b1,bg_w2,bg_b2,bg_w3,bg_b3, attn, biasO);
  else       kCD_body<false>(x, idxg, kg_w1,kg_b1,kg_w2,kg_b2,kg_w3,kg_b3,
                             bg_w1,bg_b1,bg_w2,bg_b2,bg_w3,bg_b3, attn, biasO);
}

// ---------------- Kernel F body: mix W in LDS + compact list + per-cluster conv -------------
template<bool BF>
__device__ void kF_body(const void* __restrict__ x,
                        const int* __restrict__ idxg,
                        const float* __restrict__ attn,
                        const float* __restrict__ biasO,
                        const void* __restrict__ base,
                        void* __restrict__ dout){
  int wg = blockIdx.x;
  int half = wg & 1; int bk = wg >> 1; int b = bk >> 5; int k = bk & 31;
  int t = threadIdx.x; int wv = t >> 6, lane = t & 63;

  __shared__ float Wt[32*292];   // [cl][f], stride 292
  __shared__ float at[32];
  __shared__ float bs[32];
  __shared__ int   lst[4096];
  __shared__ int   lcnt;

  if (t < 32){ at[t] = attn[bk*NBASE + t]; bs[t] = biasO[bk*COUT + half*32 + t]; }
  if (t == 0) lcnt = 0;
  __syncthreads();

  for (int e=t; e<32*FF; e+=256){
    int f = e >> 5, cl = e & 31;
    size_t bp = (size_t)f*COUT + half*32 + cl;
    float s = 0.f;
    #pragma unroll 8
    for (int n=0; n<NBASE; ++n)
      s = fmaf(at[n], ld<BF>(base, bp + (size_t)n*FF*COUT), s);
    Wt[cl*292 + f] = s;
  }

  for (int p0=0; p0<4096; p0+=256){
    int p = p0 + t;
    bool m = (idxg[b*PP + p] == k);
    unsigned long long mask = __ballot(m);
    int cw = __popcll(mask);
    int basew = 0;
    if (lane == 0 && cw) basew = atomicAdd(&lcnt, cw);
    basew = __shfl(basew, 0);
    if (m){
      int off = __popcll(mask & ((1ULL << lane) - 1ULL));
      lst[basew + off] = p;
    }
  }
  __syncthreads();

  int cnt = lcnt;
  size_t xb = (size_t)b << 17;
  for (int i0 = wv*64; i0 < cnt; i0 += 256){
    int myi = i0 + lane;
    bool hp = myi < cnt;
    int p = hp ? lst[myi] : 0;
    int h = p >> 6, w = p & 63;
    bool hm0 = h > 0, hm2 = h < 63, wm0 = w > 0, wm2 = w < 63;
    float acc[32];
    #pragma unroll
    for (int cl=0; cl<32; ++cl) acc[cl] = 0.f;
    for (int c=0; c<32; ++c){
      size_t xc = xb + ((size_t)c<<12) + (h<<6) + w;
      float v0 = (hm0&&wm0) ? ld<BF>(x, xc-65) : 0.f;
      float v1 = (hm0     ) ? ld<BF>(x, xc-64) : 0.f;
      float v2 = (hm0&&wm2) ? ld<BF>(x, xc-63) : 0.f;
      float v3 = (      wm0) ? ld<BF>(x, xc-1)  : 0.f;
      float v4 =              ld<BF>(x, xc);
      float v5 = (      wm2) ? ld<BF>(x, xc+1)  : 0.f;
      float v6 = (hm2&&wm0) ? ld<BF>(x, xc+63) : 0.f;
      float v7 = (hm2     ) ? ld<BF>(x, xc+64) : 0.f;
      float v8 = (hm2&&wm2) ? ld<BF>(x, xc+65) : 0.f;
      const float* wr = &Wt[c*9];
      #pragma unroll
      for (int cl=0; cl<32; ++cl){
        const float* wc = wr + cl*292;
        float a = acc[cl];
        a = fmaf(v0, wc[0], a); a = fmaf(v1, wc[1], a); a = fmaf(v2, wc[2], a);
        a = fmaf(v3, wc[3], a); a = fmaf(v4, wc[4], a); a = fmaf(v5, wc[5], a);
        a = fmaf(v6, wc[6], a); a = fmaf(v7, wc[7], a); a = fmaf(v8, wc[8], a);
        acc[cl] = a;
      }
    }
    if (hp){
      size_t ob = ((size_t)b*COUT + half*32)*PP + p;
      #pragma unroll
      for (int cl=0; cl<32; ++cl) st<BF>(dout, ob + (size_t)cl*PP, acc[cl] + bs[cl]);
    }
  }
}

__global__ __launch_bounds__(256) void kF(const void* x, const int* idxg,
                                          const float* attn, const float* biasO,
                                          const void* base, void* dout, const int* flag){
  if (*flag) kF_body<true >(x, idxg, attn, biasO, base, dout);
  else       kF_body<false>(x, idxg, attn, biasO, base, dout);
}

// ---------------- host: JAX threefry2x32 + permutation(key,4096)[:32] ----------------
static inline uint32_t rotl32(uint32_t x, int d){ return (x<<d)|(x>>(32-d)); }
static void tf_block(uint32_t k0,uint32_t k1,uint32_t x0,uint32_t x1,uint32_t&o0,uint32_t&o1){
  uint32_t ks2 = k0 ^ k1 ^ 0x1BD11BDAu;
  uint32_t v0 = x0 + k0, v1 = x1 + k1;
  const int ra[4]={13,15,26,6}, rb[4]={17,29,16,24};
  #define R4(r) for(int i_=0;i_<4;++i_){ v0 += v1; v1 = rotl32(v1,(r)[i_]); v1 ^= v0; }
  R4(ra); v0 += k1;  v1 += ks2 + 1u;
  R4(rb); v0 += ks2; v1 += k0  + 2u;
  R4(ra); v0 += k0;  v1 += k1  + 3u;
  R4(rb); v0 += k1;  v1 += ks2 + 4u;
  R4(ra); v0 += ks2; v1 += k0  + 5u;
  #undef R4
  o0 = v0; o1 = v1;
}
struct KP{ uint32_t a, b; };
static void tf_split(KP k, KP& first, KP& second){
#if THREEFRY_PARTITIONABLE
  uint32_t a0,b0,a1,b1;
  tf_block(k.a,k.b, 0u,0u, a0,b0);   // child i = cipher(key,(0,i))
  tf_block(k.a,k.b, 0u,1u, a1,b1);
  first  = KP{a0,b0};
  second = KP{a1,b1};
#else
  uint32_t a0,b0,a1,b1;
  tf_block(k.a,k.b, 0u,2u, a0,b0);   // halves pairing of iota(4)
  tf_block(k.a,k.b, 1u,3u, a1,b1);
  first  = KP{a0,a1};
  second = KP{b0,b1};
#endif
}
static void random_bits_4096(KP k, std::vector<uint32_t>& bits){
#if THREEFRY_PARTITIONABLE
  for (int i=0;i<4096;++i){
    uint32_t o0,o1; tf_block(k.a,k.b, 0u,(uint32_t)i, o0,o1);
    bits[i] = o0 ^ o1;
  }
#else
  for (int i=0;i<2048;++i){
    uint32_t o0,o1; tf_block(k.a,k.b,(uint32_t)i,(uint32_t)(i+2048),o0,o1);
    bits[i] = o0; bits[i+2048] = o1;
  }
#endif
}
static void perm_first32(KP key, int* out32){
  std::vector<int> vals(4096);
  for (int i=0;i<4096;++i) vals[i] = i;
  std::vector<uint32_t> bits(4096);
  std::vector<std::pair<uint32_t,int>> pr(4096);
  KP k = key;
  for (int r=0;r<2;++r){
    KP nk, sk; tf_split(k, nk, sk); k = nk;
    random_bits_4096(sk, bits);
    for (int i=0;i<4096;++i) pr[i] = std::make_pair(bits[i], vals[i]);
    std::stable_sort(pr.begin(), pr.end(),
        [](const std::pair<uint32_t,int>& a, const std::pair<uint32_t,int>& c){ return a.first < c.first; });
    for (int i=0;i<4096;++i) vals[i] = pr[i].second;
  }
  for (int j=0;j<32;++j) out32[j] = vals[j];
}

extern "C" void kernel_launch(void* const* d_in, const int* in_sizes, int n_in,
                              void* d_out, int out_size, void* d_ws, size_t ws_size,
                              hipStream_t stream) {
  const void* x     = d_in[0];
  const void* base  = d_in[1];
  const void* kg_w1 = d_in[2];
  const void* kg_b1 = d_in[3];
  const void* kg_w2 = d_in[4];
  const void* kg_b2 = d_in[5];
  const void* kg_w3 = d_in[6];
  const void* kg_b3 = d_in[7];
  const void* bg_w1 = d_in[8];
  const void* bg_b1 = d_in[9];
  const void* bg_w2 = d_in[10];
  const void* bg_b2 = d_in[11];
  const void* bg_w3 = d_in[12];
  const void* bg_b3 = d_in[13];

  char* ws = (char*)d_ws;
  int*   bar   = (int*)ws;                       // [0]=cnt [1]=gen
  int*   flag  = (int*)(ws + 64);                // dtype flag
  int*   idxg  = (int*)(ws + OFF_IDX);
  float* attn  = (float*)(ws + OFF_ATTN);
  float* biasO = (float*)(ws + OFF_BIAS);
  float* part  = (float*)(ws + OFF_PART);

  InitIdx ii;
  KP root = KP{0u, 42u};                         // threefry_seed(42)
  KP kb0, kb1; tf_split(root, kb0, kb1);         // jax.random.split(key(42), 2)
  perm_first32(kb0, ii.v[0]);
  perm_first32(kb1, ii.v[1]);

  hipMemsetAsync(ws, 0, 64, stream);             // grid barrier state

  kDetect<<<1, 256, 0, stream>>>(x, flag);
  kB<<<NWG_KM, 256, 0, stream>>>(x, part, idxg, d_out, bar, flag, ii);
  kCD<<<64, 256, 0, stream>>>(x, idxg,
                              kg_w1, kg_b1, kg_w2, kg_b2, kg_w3, kg_b3,
                              bg_w1, bg_b1, bg_w2, bg_b2, bg_w3, bg_b3,
                              attn, biasO, flag);
  kF<<<128, 256, 0, stream>>>(x, idxg, attn, biasO, base, d_out, flag);
}

// Round 4
// 589.161 us; speedup vs baseline: 1.0519x; 1.0519x over previous
//
#include <hip/hip_runtime.h>
#include <hip/hip_bf16.h>
#include <vector>
#include <algorithm>
#include <utility>
#include <stdint.h>

// Problem constants
#define BB 2
#define PP 4096        // H*W
#define FF 288         // C*9
#define KK 32
#define NBASE 32
#define HID 64
#define COUT 64
#define NWG_KM 32      // k-means workgroups (16 per batch)
#define SUBS 16
#define OUT_ELEMS 524288   // 2*64*4096; idx chunk follows

#define THREEFRY_PARTITIONABLE 1

typedef unsigned short u16;

// ---------------- ws layout (bytes), total ~3.7 MB ----------------
// [0..63] barrier (memset 0), [64..67] dtype flag (written by kDetect)
#define OFF_IDX    512          // 2*4096*4  = 32768
#define OFF_ATTN   33280        // 64*32*4   = 8192
#define OFF_BIAS   41472        // 64*64*4   = 16384
#define OFF_PART   57856        // 64*1056*4 = 270336 -> 328192
#define OFF_CPART  328192       // 32 chunks * 32 k * 289 f32 = 1183744 -> 1511936
#define OFF_WG     1511936      // 64 * 18432 u16 = 2359296 -> 3871232

struct InitIdx { int v[2][32]; };

// ---------------- device helpers ----------------
__device__ __forceinline__ float bf2f(u16 u){
  union { unsigned int i; float f; } cv; cv.i = ((unsigned int)u) << 16; return cv.f;
}
__device__ __forceinline__ u16 f2bf(float f){
  union { float f; unsigned int i; } cv; cv.f = f;
  unsigned int x = cv.i;
  unsigned int r = (x + 0x7FFFu + ((x >> 16) & 1u)) >> 16;
  return (u16)r;
}

template<bool BF>
__device__ __forceinline__ float ld(const void* p, size_t i){
  if constexpr (BF) { return bf2f(((const u16*)p)[i]); }
  else              { return ((const float*)p)[i]; }
}
template<bool BF>
__device__ __forceinline__ void st(void* p, size_t i, float v){
  if constexpr (BF) { ((u16*)p)[i] = f2bf(v); }
  else              { ((float*)p)[i] = v; }
}

template<bool BF>
__device__ __forceinline__ float obs_chan(const void* x, size_t bi, int h, int w){
  float s = 0.f;
  #pragma unroll
  for (int dh=-1; dh<=1; ++dh){
    int hh = h + dh;
    #pragma unroll
    for (int dw=-1; dw<=1; ++dw){
      int ww = w + dw;
      float v = 0.f;
      if ((unsigned)hh < 64u && (unsigned)ww < 64u) v = ld<BF>(x, bi + (hh<<6) + ww);
      s += v;
    }
  }
  return s / 9.0f;
}

__device__ __forceinline__ void gbar(int* cnt, int* gen, int nwg){
  __threadfence();
  __syncthreads();
  if (threadIdx.x == 0){
    int g = __hip_atomic_load(gen, __ATOMIC_RELAXED, __HIP_MEMORY_SCOPE_AGENT);
    int prev = __hip_atomic_fetch_add(cnt, 1, __ATOMIC_ACQ_REL, __HIP_MEMORY_SCOPE_AGENT);
    if (prev == nwg - 1){
      __hip_atomic_store(cnt, 0, __ATOMIC_RELAXED, __HIP_MEMORY_SCOPE_AGENT);
      __hip_atomic_fetch_add(gen, 1, __ATOMIC_RELEASE, __HIP_MEMORY_SCOPE_AGENT);
    } else {
      while (__hip_atomic_load(gen, __ATOMIC_ACQUIRE, __HIP_MEMORY_SCOPE_AGENT) == g){
        __builtin_amdgcn_s_sleep(8);
      }
    }
  }
  __syncthreads();
  __threadfence();
}

// ---------------- Kernel 0: input dtype detection (unchanged, it works) ----------------
__global__ __launch_bounds__(256) void kDetect(const void* __restrict__ x, int* flag){
  __shared__ int cnt;
  if (threadIdx.x == 0) cnt = 0;
  __syncthreads();
  const u16* p = (const u16*)x;
  int bad = 0;
  for (int i = threadIdx.x; i < 1024; i += 256){
    u16 u = p[2*i];
    unsigned e = (u >> 7) & 0xFFu;
    if (e >= 131u) ++bad;
  }
  atomicAdd(&cnt, bad);
  __syncthreads();
  if (threadIdx.x == 0) *flag = (cnt < 102) ? 1 : 0;
}

// ---------------- Kernel B: persistent k-means (FROZEN — exact semantics passed R3) --------
template<bool BF>
__device__ void kB_body(const void* __restrict__ x,
                        float* __restrict__ part,
                        int* __restrict__ idxg,
                        void* __restrict__ dout,
                        int* __restrict__ bar,
                        const InitIdx& ii){
  const int t   = threadIdx.x;
  const int wg  = blockIdx.x;
  const int mb  = wg >> 4;
  const int sub = wg & 15;
  const int pg  = sub*256 + t;

  __shared__ float obs_st[256][33];
  __shared__ float cent[2][32][32];
  __shared__ float cc_s[32];
  __shared__ int   a_loc[256];
  __shared__ float sq[32][32];
  __shared__ float snorm[32];
  __shared__ float cntsh[32];

  float o[32];
  {
    int h = pg >> 6, w = pg & 63;
    size_t xb = (size_t)mb << 17;
    for (int c=0; c<32; ++c){
      float v = obs_chan<BF>(x, xb + ((size_t)c<<12), h, w);
      o[c] = v; obs_st[t][c] = v;
    }
  }
  if (t < 64){
    int bb = t >> 5, j = t & 31;
    int q = ii.v[bb][j];
    int qh = q >> 6, qw = q & 63;
    size_t xq = (size_t)bb << 17;
    for (int c=0; c<32; ++c) cent[bb][j][c] = obs_chan<BF>(x, xq + ((size_t)c<<12), qh, qw);
  }
  __syncthreads();

  float ss = 0.f;
  #pragma unroll
  for (int d=0; d<32; ++d) ss = fmaf(o[d], o[d], ss);

  bool act0 = true, act1 = true;
  int parity = 0;

  for (int it=0; it<20; ++it){
    if (!(act0 || act1)) break;
    bool mine = (mb==0) ? act0 : act1;
    if (mine){
      if (t < 32){
        float s = 0.f;
        #pragma unroll
        for (int d=0; d<32; ++d){ float v = cent[mb][t][d]; s = fmaf(v,v,s); }
        cc_s[t] = s;
      }
      __syncthreads();
      float best = 3.0e38f; int bk = 0;
      for (int k=0; k<32; ++k){
        const float* cr = &cent[mb][k][0];
        float dot = 0.f;
        #pragma unroll
        for (int d=0; d<32; ++d) dot = fmaf(o[d], cr[d], dot);
        float dist = (ss - 2.0f*dot) + cc_s[k];
        if (dist < best){ best = dist; bk = k; }
      }
      a_loc[t] = bk;
      __syncthreads();
      const int d = t & 31, g = t >> 5;
      float s0=0.f, s1=0.f, s2=0.f, s3=0.f;
      #pragma unroll 4
      for (int p=0; p<256; ++p){
        int ap = a_loc[p];
        float v = obs_st[p][d];
        s0 += (ap==g     ) ? v : 0.f;
        s1 += (ap==g + 8 ) ? v : 0.f;
        s2 += (ap==g + 16) ? v : 0.f;
        s3 += (ap==g + 24) ? v : 0.f;
      }
      float* Pg = part + ((size_t)((parity*2 + mb)*SUBS + sub))*1056;
      __hip_atomic_store(Pg + (g    )*33 + d, s0, __ATOMIC_RELAXED, __HIP_MEMORY_SCOPE_AGENT);
      __hip_atomic_store(Pg + (g+ 8 )*33 + d, s1, __ATOMIC_RELAXED, __HIP_MEMORY_SCOPE_AGENT);
      __hip_atomic_store(Pg + (g+16 )*33 + d, s2, __ATOMIC_RELAXED, __HIP_MEMORY_SCOPE_AGENT);
      __hip_atomic_store(Pg + (g+24 )*33 + d, s3, __ATOMIC_RELAXED, __HIP_MEMORY_SCOPE_AGENT);
      if (t < 32){
        int cnt_ = 0;
        #pragma unroll 4
        for (int p=0; p<256; ++p) cnt_ += (a_loc[p] == t) ? 1 : 0;
        __hip_atomic_store(Pg + t*33 + 32, (float)cnt_, __ATOMIC_RELAXED, __HIP_MEMORY_SCOPE_AGENT);
      }
    }
    gbar(bar, bar+1, NWG_KM);
    for (int bb=0; bb<2; ++bb){
      bool ab = (bb==0) ? act0 : act1;
      if (!ab) continue;
      const float* Pb = part + ((size_t)((parity*2 + bb)*SUBS))*1056;
      if (t < 32){
        float s = 0.f;
        for (int si=0; si<SUBS; ++si)
          s += __hip_atomic_load(Pb + (size_t)si*1056 + t*33 + 32, __ATOMIC_RELAXED, __HIP_MEMORY_SCOPE_AGENT);
        cntsh[t] = s;
      }
      __syncthreads();
      for (int e=t; e<1024; e+=256){
        int k = e >> 5, d = e & 31;
        float s = 0.f;
        for (int si=0; si<SUBS; ++si)
          s += __hip_atomic_load(Pb + (size_t)si*1056 + k*33 + d, __ATOMIC_RELAXED, __HIP_MEMORY_SCOPE_AGENT);
        float oldv = cent[bb][k][d];
        float cn = cntsh[k];
        float nv = (cn > 0.f) ? (s / fmaxf(cn, 1.f)) : oldv;
        float dd = nv - oldv;
        sq[k][d] = dd*dd;
        cent[bb][k][d] = nv;
      }
      __syncthreads();
      if (t < 32){
        float s = 0.f;
        #pragma unroll
        for (int d=0; d<32; ++d) s += sq[t][d];
        snorm[t] = sqrtf(s);
      }
      __syncthreads();
      float sh = 0.f;
      for (int k=0;k<32;++k) sh += snorm[k];
      bool na = ((it+1) < 20) && ((double)sh >= 20.48);
      if (bb==0) act0 = na; else act1 = na;
      __syncthreads();
    }
    parity ^= 1;
  }
  __syncthreads();
  if (t < 32){
    float s = 0.f;
    #pragma unroll
    for (int d=0; d<32; ++d){ float v = cent[mb][t][d]; s = fmaf(v,v,s); }
    cc_s[t] = s;
  }
  __syncthreads();
  float best = 3.0e38f; int bk = 0;
  for (int k=0; k<32; ++k){
    const float* cr = &cent[mb][k][0];
    float dot = 0.f;
    #pragma unroll
    for (int d=0; d<32; ++d) dot = fmaf(o[d], cr[d], dot);
    float dist = (ss - 2.0f*dot) + cc_s[k];
    if (dist < best){ best = dist; bk = k; }
  }
  idxg[mb*PP + pg] = bk;
  st<BF>(dout, (size_t)OUT_ELEMS + mb*PP + pg, (float)bk);
}

__global__ __launch_bounds__(256) void kB(const void* x, float* part, int* idxg,
                                          void* dout, int* bar, const int* flag, InitIdx ii){
  if (*flag) kB_body<true >(x, part, idxg, dout, bar, ii);
  else       kB_body<false>(x, part, idxg, dout, bar, ii);
}

// ---------------- Kernel C: point-parallel cluster patch sums ----------------
// grid 32: wg = (b, chunk of 256 points). lane = point (coalesced x), loop f,
// LDS-atomic acc[k*289 + f] (289 stride: distinct k -> distinct banks).
template<bool BF>
__device__ void kC_body(const void* __restrict__ x,
                        const int* __restrict__ idxg,
                        float* __restrict__ cpart,
                        float* __restrict__ acc){
  int cg = blockIdx.x;            // 0..31
  int b = cg >> 4, pc = cg & 15;
  int t = threadIdx.x;
  for (int e=t; e<32*289; e+=256) acc[e] = 0.f;
  __syncthreads();
  int p = pc*256 + t;
  int h = p >> 6, w = p & 63;
  int k = idxg[b*PP + p];
  size_t xb = (size_t)b << 17;
  // count
  atomicAdd(&acc[k*289 + 288], 1.0f);
  // features
  for (int f=0; f<FF; ++f){
    int c = f / 9, j = f % 9;
    int hh = h + j/3 - 1, ww = w + j%3 - 1;
    float v = 0.f;
    if ((unsigned)hh < 64u && (unsigned)ww < 64u)
      v = ld<BF>(x, xb + ((size_t)c<<12) + (hh<<6) + ww);
    atomicAdd(&acc[k*289 + f], v);
  }
  __syncthreads();
  float* cp = cpart + (size_t)cg*(32*289);
  for (int e=t; e<32*289; e+=256) cp[e] = acc[e];
}

__global__ __launch_bounds__(256) void kC(const void* x, const int* idxg,
                                          float* cpart, const int* flag){
  __shared__ float acc[32*289];
  if (*flag) kC_body<true >(x, idxg, cpart, acc);
  else       kC_body<false>(x, idxg, cpart, acc);
}

// ---------------- Kernel D: merge partials -> centers + 2 MLPs + softmax ----------------
template<bool BF>
__device__ void kD_body(const float* __restrict__ cpart,
                        const void* kg_w1, const void* kg_b1,
                        const void* kg_w2, const void* kg_b2,
                        const void* kg_w3, const void* kg_b3,
                        const void* bg_w1, const void* bg_b1,
                        const void* bg_w2, const void* bg_b2,
                        const void* bg_w3, const void* bg_b3,
                        float* __restrict__ attn,
                        float* __restrict__ biasO,
                        float* __restrict__ row,
                        float* __restrict__ h1,
                        float* __restrict__ h2,
                        float* __restrict__ lgs){
  int wg = blockIdx.x; int b = wg >> 5; int k = wg & 31;
  int t = threadIdx.x;   // 64 threads
  // counts (deterministic merge order ch=0..15)
  float cnt = 0.f;
  for (int ch=0; ch<16; ++ch)
    cnt += cpart[((size_t)(b*16+ch)*32 + k)*289 + 288];
  float den = fmaxf(cnt, 1.f);
  for (int f=t; f<FF; f+=64){
    float s = 0.f;
    for (int ch=0; ch<16; ++ch)
      s += cpart[((size_t)(b*16+ch)*32 + k)*289 + f];
    row[f] = s / den;
  }
  __syncthreads();

  {
    float s = 0.f;
    #pragma unroll 8
    for (int f=0; f<FF; ++f) s = fmaf(row[f], ld<BF>(kg_w1, f*HID + t), s);
    h1[t] = fmaxf(s + ld<BF>(kg_b1, t), 0.f);
  }
  __syncthreads();
  {
    float s = 0.f;
    #pragma unroll 8
    for (int h=0; h<HID; ++h) s = fmaf(h1[h], ld<BF>(kg_w2, h*HID + t), s);
    h2[t] = fmaxf(s + ld<BF>(kg_b2, t), 0.f);
  }
  __syncthreads();
  if (t < 32){
    float s = 0.f;
    #pragma unroll 8
    for (int h=0; h<HID; ++h) s = fmaf(h2[h], ld<BF>(kg_w3, h*NBASE + t), s);
    lgs[t] = s + ld<BF>(kg_b3, t);
  }
  __syncthreads();
  if (t < 32){
    float mx = -3.0e38f;
    for (int i=0;i<NBASE;++i) mx = fmaxf(mx, lgs[i]);
    float se = 0.f;
    for (int i=0;i<NBASE;++i) se += expf(lgs[i]-mx);
    attn[wg*NBASE + t] = expf(lgs[t]-mx) / se;
  }
  __syncthreads();
  {
    float s = 0.f;
    #pragma unroll 8
    for (int f=0; f<FF; ++f) s = fmaf(row[f], ld<BF>(bg_w1, f*HID + t), s);
    h1[t] = fmaxf(s + ld<BF>(bg_b1, t), 0.f);
  }
  __syncthreads();
  {
    float s = 0.f;
    #pragma unroll 8
    for (int h=0; h<HID; ++h) s = fmaf(h1[h], ld<BF>(bg_w2, h*HID + t), s);
    h2[t] = fmaxf(s + ld<BF>(bg_b2, t), 0.f);
  }
  __syncthreads();
  {
    float s = 0.f;
    #pragma unroll 8
    for (int h=0; h<HID; ++h) s = fmaf(h2[h], ld<BF>(bg_w3, h*COUT + t), s);
    biasO[wg*COUT + t] = s + ld<BF>(bg_b3, t);
  }
}

__global__ __launch_bounds__(64) void kD(const float* cpart,
                                         const void* kg_w1, const void* kg_b1,
                                         const void* kg_w2, const void* kg_b2,
                                         const void* kg_w3, const void* kg_b3,
                                         const void* bg_w1, const void* bg_b1,
                                         const void* bg_w2, const void* bg_b2,
                                         const void* bg_w3, const void* bg_b3,
                                         float* attn, float* biasO, const int* flag){
  __shared__ float row[FF];
  __shared__ float h1[64];
  __shared__ float h2[64];
  __shared__ float lgs[32];
  if (*flag) kD_body<true >(cpart, kg_w1,kg_b1,kg_w2,kg_b2,kg_w3,kg_b3,
                            bg_w1,bg_b1,bg_w2,bg_b2,bg_w3,bg_b3, attn, biasO, row,h1,h2,lgs);
  else       kD_body<false>(cpart, kg_w1,kg_b1,kg_w2,kg_b2,kg_w3,kg_b3,
                            bg_w1,bg_b1,bg_w2,bg_b2,bg_w3,bg_b3, attn, biasO, row,h1,h2,lgs);
}

// ---------------- Kernel E: Wg[b,k,f,c] (bf16) = sum_n attn*base ----------------
// grid 256: wg = (bk, f-quarter of 72)
template<bool BF>
__device__ void kE_body(const void* __restrict__ base,
                        const float* __restrict__ attn,
                        u16* __restrict__ Wg,
                        float* __restrict__ at){
  int wg = blockIdx.x;
  int fq = wg & 3, bk = wg >> 2;
  int t = threadIdx.x;
  if (t < 32) at[t] = attn[bk*NBASE + t];
  __syncthreads();
  int f0 = fq*72;
  for (int e=t; e<72*64; e+=256){
    int fl = e >> 6, c = e & 63;
    size_t bi = (size_t)(f0 + fl)*COUT + c;
    float s = 0.f;
    #pragma unroll 8
    for (int n=0; n<NBASE; ++n)
      s = fmaf(at[n], ld<BF>(base, bi + (size_t)n*FF*COUT), s);
    Wg[(size_t)bk*(FF*COUT) + (f0+fl)*COUT + c] = f2bf(s);
  }
}

__global__ __launch_bounds__(256) void kE(const void* base, const float* attn,
                                          u16* Wg, const int* flag){
  __shared__ float at[32];
  if (*flag) kE_body<true >(base, attn, Wg, at);
  else       kE_body<false>(base, attn, Wg, at);
}

// ---------------- Kernel F: spatial-major conv ----------------
// grid 512: wg = (b, h, quarter-row of 16 points). wave = one point x 64 couts.
// x tile in LDS as [r(3)][col(18)][c(32)] stride 36 -> float4 reads, broadcast.
template<bool BF>
__device__ void kF_body(const void* __restrict__ x,
                        const int* __restrict__ idxg,
                        const u16* __restrict__ Wg,
                        const float* __restrict__ biasO,
                        void* __restrict__ dout,
                        float* __restrict__ xs){
  int wg = blockIdx.x;
  int q = wg & 3, h = (wg >> 2) & 63, b = wg >> 8;
  int t = threadIdx.x, wv = t >> 6, lane = t & 63;
  int w0 = q << 4;

  // stage tile: global-coalesced read order (c, r, col), LDS write (r*18+col)*36 + c
  for (int e=t; e<32*54; e+=256){
    int c = e / 54, rem = e % 54;
    int r = rem / 18, col = rem % 18;
    int gr = h - 1 + r, gc = w0 - 1 + col;
    float v = 0.f;
    if ((unsigned)gr < 64u && (unsigned)gc < 64u)
      v = ld<BF>(x, ((size_t)b << 17) + ((size_t)c << 12) + (gr << 6) + gc);
    xs[(r*18 + col)*36 + c] = v;
  }
  __syncthreads();

  #pragma unroll
  for (int i=0; i<4; ++i){
    int pl = (wv << 2) + i;        // local point 0..15
    int w = w0 + pl;
    int p = (h << 6) + w;
    int k = idxg[(b << 12) + p];
    const u16* Wr = Wg + (size_t)((b << 5) + k)*(FF*COUT) + lane;
    float acc = 0.f;
    for (int r=0; r<3; ++r){
      #pragma unroll
      for (int dw=0; dw<3; ++dw){
        const float4* xv = (const float4*)(xs + (r*18 + pl + dw)*36);
        int rd = r*3 + dw;
        #pragma unroll
        for (int c4=0; c4<8; ++c4){
          float4 v = xv[c4];
          int cb = c4 << 2;
          acc = fmaf(v.x, bf2f(Wr[((cb+0)*9 + rd) << 6]), acc);
          acc = fmaf(v.y, bf2f(Wr[((cb+1)*9 + rd) << 6]), acc);
          acc = fmaf(v.z, bf2f(Wr[((cb+2)*9 + rd) << 6]), acc);
          acc = fmaf(v.w, bf2f(Wr[((cb+3)*9 + rd) << 6]), acc);
        }
      }
    }
    float bias = biasO[((b << 5) + k)*COUT + lane];
    st<BF>(dout, ((size_t)((b << 6) + lane) << 12) + p, acc + bias);
  }
}

__global__ __launch_bounds__(256) void kF(const void* x, const int* idxg,
                                          const u16* Wg, const float* biasO,
                                          void* dout, const int* flag){
  __shared__ float xs[3*18*36];
  if (*flag) kF_body<true >(x, idxg, Wg, biasO, dout, xs);
  else       kF_body<false>(x, idxg, Wg, biasO, dout, xs);
}

// ---------------- host: JAX threefry2x32 + permutation(key,4096)[:32] ----------------
static inline uint32_t rotl32(uint32_t x, int d){ return (x<<d)|(x>>(32-d)); }
static void tf_block(uint32_t k0,uint32_t k1,uint32_t x0,uint32_t x1,uint32_t&o0,uint32_t&o1){
  uint32_t ks2 = k0 ^ k1 ^ 0x1BD11BDAu;
  uint32_t v0 = x0 + k0, v1 = x1 + k1;
  const int ra[4]={13,15,26,6}, rb[4]={17,29,16,24};
  #define R4(r) for(int i_=0;i_<4;++i_){ v0 += v1; v1 = rotl32(v1,(r)[i_]); v1 ^= v0; }
  R4(ra); v0 += k1;  v1 += ks2 + 1u;
  R4(rb); v0 += ks2; v1 += k0  + 2u;
  R4(ra); v0 += k0;  v1 += k1  + 3u;
  R4(rb); v0 += k1;  v1 += ks2 + 4u;
  R4(ra); v0 += ks2; v1 += k0  + 5u;
  #undef R4
  o0 = v0; o1 = v1;
}
struct KP{ uint32_t a, b; };
static void tf_split(KP k, KP& first, KP& second){
#if THREEFRY_PARTITIONABLE
  uint32_t a0,b0,a1,b1;
  tf_block(k.a,k.b, 0u,0u, a0,b0);
  tf_block(k.a,k.b, 0u,1u, a1,b1);
  first  = KP{a0,b0};
  second = KP{a1,b1};
#else
  uint32_t a0,b0,a1,b1;
  tf_block(k.a,k.b, 0u,2u, a0,b0);
  tf_block(k.a,k.b, 1u,3u, a1,b1);
  first  = KP{a0,a1};
  second = KP{b0,b1};
#endif
}
static void random_bits_4096(KP k, std::vector<uint32_t>& bits){
#if THREEFRY_PARTITIONABLE
  for (int i=0;i<4096;++i){
    uint32_t o0,o1; tf_block(k.a,k.b, 0u,(uint32_t)i, o0,o1);
    bits[i] = o0 ^ o1;
  }
#else
  for (int i=0;i<2048;++i){
    uint32_t o0,o1; tf_block(k.a,k.b,(uint32_t)i,(uint32_t)(i+2048),o0,o1);
    bits[i] = o0; bits[i+2048] = o1;
  }
#endif
}
static void perm_first32(KP key, int* out32){
  std::vector<int> vals(4096);
  for (int i=0;i<4096;++i) vals[i] = i;
  std::vector<uint32_t> bits(4096);
  std::vector<std::pair<uint32_t,int>> pr(4096);
  KP k = key;
  for (int r=0;r<2;++r){
    KP nk, sk; tf_split(k, nk, sk); k = nk;
    random_bits_4096(sk, bits);
    for (int i=0;i<4096;++i) pr[i] = std::make_pair(bits[i], vals[i]);
    std::stable_sort(pr.begin(), pr.end(),
        [](const std::pair<uint32_t,int>& a, const std::pair<uint32_t,int>& c){ return a.first < c.first; });
    for (int i=0;i<4096;++i) vals[i] = pr[i].second;
  }
  for (int j=0;j<32;++j) out32[j] = vals[j];
}

extern "C" void kernel_launch(void* const* d_in, const int* in_sizes, int n_in,
                              void* d_out, int out_size, void* d_ws, size_t ws_size,
                              hipStream_t stream) {
  const void* x     = d_in[0];
  const void* base  = d_in[1];
  const void* kg_w1 = d_in[2];
  const void* kg_b1 = d_in[3];
  const void* kg_w2 = d_in[4];
  const void* kg_b2 = d_in[5];
  const void* kg_w3 = d_in[6];
  const void* kg_b3 = d_in[7];
  const void* bg_w1 = d_in[8];
  const void* bg_b1 = d_in[9];
  const void* bg_w2 = d_in[10];
  const void* bg_b2 = d_in[11];
  const void* bg_w3 = d_in[12];
  const void* bg_b3 = d_in[13];

  char* ws = (char*)d_ws;
  int*   bar   = (int*)ws;
  int*   flag  = (int*)(ws + 64);
  int*   idxg  = (int*)(ws + OFF_IDX);
  float* attn  = (float*)(ws + OFF_ATTN);
  float* biasO = (float*)(ws + OFF_BIAS);
  float* part  = (float*)(ws + OFF_PART);
  float* cpart = (float*)(ws + OFF_CPART);
  u16*   Wg    = (u16*)(ws + OFF_WG);

  InitIdx ii;
  KP root = KP{0u, 42u};
  KP kb0, kb1; tf_split(root, kb0, kb1);
  perm_first32(kb0, ii.v[0]);
  perm_first32(kb1, ii.v[1]);

  hipMemsetAsync(ws, 0, 64, stream);

  kDetect<<<1, 256, 0, stream>>>(x, flag);
  kB<<<NWG_KM, 256, 0, stream>>>(x, part, idxg, d_out, bar, flag, ii);
  kC<<<32, 256, 0, stream>>>(x, idxg, cpart, flag);
  kD<<<64, 64, 0, stream>>>(cpart,
                            kg_w1, kg_b1, kg_w2, kg_b2, kg_w3, kg_b3,
                            bg_w1, bg_b1, bg_w2, bg_b2, bg_w3, bg_b3,
                            attn, biasO, flag);
  kE<<<256, 256, 0, stream>>>(base, attn, Wg, flag);
  kF<<<512, 256, 0, stream>>>(x, idxg, Wg, biasO, d_out, flag);
}

// Round 5
// 436.438 us; speedup vs baseline: 1.4200x; 1.3499x over previous
//
#include <hip/hip_runtime.h>
#include <hip/hip_bf16.h>
#include <vector>
#include <algorithm>
#include <utility>
#include <stdint.h>

// Problem constants
#define BB 2
#define PP 4096        // H*W
#define FF 288         // C*9
#define KK 32
#define NBASE 32
#define HID 64
#define COUT 64
#define NWG_KM 32      // k-means workgroups (16 per batch)
#define SUBS 16
#define OUT_ELEMS 524288   // 2*64*4096; idx chunk follows

#define THREEFRY_PARTITIONABLE 1

typedef unsigned short u16;

// ---------------- ws layout (bytes) ----------------
// [0..63] barrier (memset 0), [64..67] dtype flag
#define OFF_IDX    512          // 2*4096*4  = 32768
#define OFF_ATTN   33280        // 64*32*4   = 8192
#define OFF_BIAS   41472        // 64*64*4   = 16384
#define OFF_PART   57856        // 64*1056*4 = 270336 -> 328192
#define OFF_CPART  328192       // 32 chunks * 32 k * 289 f32 = 1183744 -> 1511936
#define OFF_WG     1511936      // 64 * 64 * 288 u16 (b,k,cout,f) = 2359296 -> 3871232

struct InitIdx { int v[2][32]; };

// ---------------- device helpers ----------------
__device__ __forceinline__ float bf2f(u16 u){
  union { unsigned int i; float f; } cv; cv.i = ((unsigned int)u) << 16; return cv.f;
}
__device__ __forceinline__ u16 f2bf(float f){
  union { float f; unsigned int i; } cv; cv.f = f;
  unsigned int x = cv.i;
  unsigned int r = (x + 0x7FFFu + ((x >> 16) & 1u)) >> 16;
  return (u16)r;
}
__device__ __forceinline__ float u_lo(unsigned int u){
  union { unsigned int i; float f; } cv; cv.i = u << 16; return cv.f;
}
__device__ __forceinline__ float u_hi(unsigned int u){
  union { unsigned int i; float f; } cv; cv.i = u & 0xFFFF0000u; return cv.f;
}

template<bool BF>
__device__ __forceinline__ float ld(const void* p, size_t i){
  if constexpr (BF) { return bf2f(((const u16*)p)[i]); }
  else              { return ((const float*)p)[i]; }
}
template<bool BF>
__device__ __forceinline__ void st(void* p, size_t i, float v){
  if constexpr (BF) { ((u16*)p)[i] = f2bf(v); }
  else              { ((float*)p)[i] = v; }
}

template<bool BF>
__device__ __forceinline__ float obs_chan(const void* x, size_t bi, int h, int w){
  float s = 0.f;
  #pragma unroll
  for (int dh=-1; dh<=1; ++dh){
    int hh = h + dh;
    #pragma unroll
    for (int dw=-1; dw<=1; ++dw){
      int ww = w + dw;
      float v = 0.f;
      if ((unsigned)hh < 64u && (unsigned)ww < 64u) v = ld<BF>(x, bi + (hh<<6) + ww);
      s += v;
    }
  }
  return s / 9.0f;
}

__device__ __forceinline__ void gbar(int* cnt, int* gen, int nwg){
  __threadfence();
  __syncthreads();
  if (threadIdx.x == 0){
    int g = __hip_atomic_load(gen, __ATOMIC_RELAXED, __HIP_MEMORY_SCOPE_AGENT);
    int prev = __hip_atomic_fetch_add(cnt, 1, __ATOMIC_ACQ_REL, __HIP_MEMORY_SCOPE_AGENT);
    if (prev == nwg - 1){
      __hip_atomic_store(cnt, 0, __ATOMIC_RELAXED, __HIP_MEMORY_SCOPE_AGENT);
      __hip_atomic_fetch_add(gen, 1, __ATOMIC_RELEASE, __HIP_MEMORY_SCOPE_AGENT);
    } else {
      while (__hip_atomic_load(gen, __ATOMIC_ACQUIRE, __HIP_MEMORY_SCOPE_AGENT) == g){
        __builtin_amdgcn_s_sleep(2);
      }
    }
  }
  __syncthreads();
  __threadfence();
}

// ---------------- Kernel 0: input dtype detection ----------------
__global__ __launch_bounds__(256) void kDetect(const void* __restrict__ x, int* flag){
  __shared__ int cnt;
  if (threadIdx.x == 0) cnt = 0;
  __syncthreads();
  const u16* p = (const u16*)x;
  int bad = 0;
  for (int i = threadIdx.x; i < 1024; i += 256){
    u16 u = p[2*i];
    unsigned e = (u >> 7) & 0xFFu;
    if (e >= 131u) ++bad;
  }
  atomicAdd(&cnt, bad);
  __syncthreads();
  if (threadIdx.x == 0) *flag = (cnt < 102) ? 1 : 0;
}

// ---------------- Kernel B: persistent k-means (semantics FROZEN; float4 loads only) -------
template<bool BF>
__device__ void kB_body(const void* __restrict__ x,
                        float* __restrict__ part,
                        int* __restrict__ idxg,
                        void* __restrict__ dout,
                        int* __restrict__ bar,
                        const InitIdx& ii){
  const int t   = threadIdx.x;
  const int wg  = blockIdx.x;
  const int mb  = wg >> 4;
  const int sub = wg & 15;
  const int pg  = sub*256 + t;

  __shared__ float obs_st[256][33];
  __shared__ float cent[2][32][32];
  __shared__ float cc_s[32];
  __shared__ int   a_loc[256];
  __shared__ float sq[32][32];
  __shared__ float snorm[32];
  __shared__ float cntsh[32];

  float o[32];
  {
    int h = pg >> 6, w = pg & 63;
    size_t xb = (size_t)mb << 17;
    for (int c=0; c<32; ++c){
      float v = obs_chan<BF>(x, xb + ((size_t)c<<12), h, w);
      o[c] = v; obs_st[t][c] = v;
    }
  }
  if (t < 64){
    int bb = t >> 5, j = t & 31;
    int q = ii.v[bb][j];
    int qh = q >> 6, qw = q & 63;
    size_t xq = (size_t)bb << 17;
    for (int c=0; c<32; ++c) cent[bb][j][c] = obs_chan<BF>(x, xq + ((size_t)c<<12), qh, qw);
  }
  __syncthreads();

  float ss = 0.f;
  #pragma unroll
  for (int d=0; d<32; ++d) ss = fmaf(o[d], o[d], ss);

  bool act0 = true, act1 = true;
  int parity = 0;

  for (int it=0; it<20; ++it){
    if (!(act0 || act1)) break;
    bool mine = (mb==0) ? act0 : act1;
    if (mine){
      if (t < 32){
        float s = 0.f;
        #pragma unroll
        for (int d=0; d<32; ++d){ float v = cent[mb][t][d]; s = fmaf(v,v,s); }
        cc_s[t] = s;
      }
      __syncthreads();
      float best = 3.0e38f; int bk = 0;
      for (int k=0; k<32; ++k){
        const float4* cr4 = (const float4*)&cent[mb][k][0];
        float dot = 0.f;
        #pragma unroll
        for (int d4=0; d4<8; ++d4){
          float4 c4 = cr4[d4];
          dot = fmaf(o[d4*4+0], c4.x, dot);
          dot = fmaf(o[d4*4+1], c4.y, dot);
          dot = fmaf(o[d4*4+2], c4.z, dot);
          dot = fmaf(o[d4*4+3], c4.w, dot);
        }
        float dist = (ss - 2.0f*dot) + cc_s[k];
        if (dist < best){ best = dist; bk = k; }
      }
      a_loc[t] = bk;
      __syncthreads();
      const int d = t & 31, g = t >> 5;
      float s0=0.f, s1=0.f, s2=0.f, s3=0.f;
      #pragma unroll 4
      for (int p=0; p<256; ++p){
        int ap = a_loc[p];
        float v = obs_st[p][d];
        s0 += (ap==g     ) ? v : 0.f;
        s1 += (ap==g + 8 ) ? v : 0.f;
        s2 += (ap==g + 16) ? v : 0.f;
        s3 += (ap==g + 24) ? v : 0.f;
      }
      float* Pg = part + ((size_t)((parity*2 + mb)*SUBS + sub))*1056;
      __hip_atomic_store(Pg + (g    )*33 + d, s0, __ATOMIC_RELAXED, __HIP_MEMORY_SCOPE_AGENT);
      __hip_atomic_store(Pg + (g+ 8 )*33 + d, s1, __ATOMIC_RELAXED, __HIP_MEMORY_SCOPE_AGENT);
      __hip_atomic_store(Pg + (g+16 )*33 + d, s2, __ATOMIC_RELAXED, __HIP_MEMORY_SCOPE_AGENT);
      __hip_atomic_store(Pg + (g+24 )*33 + d, s3, __ATOMIC_RELAXED, __HIP_MEMORY_SCOPE_AGENT);
      if (t < 32){
        int cnt_ = 0;
        #pragma unroll 4
        for (int p=0; p<256; ++p) cnt_ += (a_loc[p] == t) ? 1 : 0;
        __hip_atomic_store(Pg + t*33 + 32, (float)cnt_, __ATOMIC_RELAXED, __HIP_MEMORY_SCOPE_AGENT);
      }
    }
    gbar(bar, bar+1, NWG_KM);
    for (int bb=0; bb<2; ++bb){
      bool ab = (bb==0) ? act0 : act1;
      if (!ab) continue;
      const float* Pb = part + ((size_t)((parity*2 + bb)*SUBS))*1056;
      if (t < 32){
        float s = 0.f;
        for (int si=0; si<SUBS; ++si)
          s += __hip_atomic_load(Pb + (size_t)si*1056 + t*33 + 32, __ATOMIC_RELAXED, __HIP_MEMORY_SCOPE_AGENT);
        cntsh[t] = s;
      }
      __syncthreads();
      for (int e=t; e<1024; e+=256){
        int k = e >> 5, d = e & 31;
        float s = 0.f;
        for (int si=0; si<SUBS; ++si)
          s += __hip_atomic_load(Pb + (size_t)si*1056 + k*33 + d, __ATOMIC_RELAXED, __HIP_MEMORY_SCOPE_AGENT);
        float oldv = cent[bb][k][d];
        float cn = cntsh[k];
        float nv = (cn > 0.f) ? (s / fmaxf(cn, 1.f)) : oldv;
        float dd = nv - oldv;
        sq[k][d] = dd*dd;
        cent[bb][k][d] = nv;
      }
      __syncthreads();
      if (t < 32){
        float s = 0.f;
        #pragma unroll
        for (int d=0; d<32; ++d) s += sq[t][d];
        snorm[t] = sqrtf(s);
      }
      __syncthreads();
      float sh = 0.f;
      for (int k=0;k<32;++k) sh += snorm[k];
      bool na = ((it+1) < 20) && ((double)sh >= 20.48);
      if (bb==0) act0 = na; else act1 = na;
      __syncthreads();
    }
    parity ^= 1;
  }
  __syncthreads();
  if (t < 32){
    float s = 0.f;
    #pragma unroll
    for (int d=0; d<32; ++d){ float v = cent[mb][t][d]; s = fmaf(v,v,s); }
    cc_s[t] = s;
  }
  __syncthreads();
  float best = 3.0e38f; int bk = 0;
  for (int k=0; k<32; ++k){
    const float4* cr4 = (const float4*)&cent[mb][k][0];
    float dot = 0.f;
    #pragma unroll
    for (int d4=0; d4<8; ++d4){
      float4 c4 = cr4[d4];
      dot = fmaf(o[d4*4+0], c4.x, dot);
      dot = fmaf(o[d4*4+1], c4.y, dot);
      dot = fmaf(o[d4*4+2], c4.z, dot);
      dot = fmaf(o[d4*4+3], c4.w, dot);
    }
    float dist = (ss - 2.0f*dot) + cc_s[k];
    if (dist < best){ best = dist; bk = k; }
  }
  idxg[mb*PP + pg] = bk;
  st<BF>(dout, (size_t)OUT_ELEMS + mb*PP + pg, (float)bk);
}

__global__ __launch_bounds__(256) void kB(const void* x, float* part, int* idxg,
                                          void* dout, int* bar, const int* flag, InitIdx ii){
  if (*flag) kB_body<true >(x, part, idxg, dout, bar, ii);
  else       kB_body<false>(x, part, idxg, dout, bar, ii);
}

// ---------------- Kernel C: cluster patch sums via wave segmented scan ----------------
// grid 32: wg = (b, chunk of 256 points = 4 rows); wave = one full row (lane = w).
// Segmented inclusive scan over same-k runs; tail lanes do the LDS atomic.
template<bool BF>
__device__ void kC_body(const void* __restrict__ x,
                        const int* __restrict__ idxg,
                        float* __restrict__ cpart,
                        float* __restrict__ acc){
  int cg = blockIdx.x;            // 0..31
  int b = cg >> 4, pc = cg & 15;
  int t = threadIdx.x;
  int lane = t & 63;
  for (int e=t; e<32*289; e+=256) acc[e] = 0.f;
  __syncthreads();
  int p = pc*256 + t;
  int h = p >> 6, w = p & 63;
  int k = idxg[b*PP + p];
  size_t xb = (size_t)b << 17;

  bool same[6];
  #pragma unroll
  for (int s=0; s<6; ++s){
    int d = 1 << s;
    int ku = __shfl_up(k, d);
    same[s] = (lane >= d) && (ku == k);
  }
  int kd = __shfl_down(k, 1);
  bool tail = (lane == 63) || (kd != k);

  // counts
  {
    float v = 1.0f;
    #pragma unroll
    for (int s=0; s<6; ++s){
      float u = __shfl_up(v, 1 << s);
      v += same[s] ? u : 0.f;
    }
    if (tail) atomicAdd(&acc[k*289 + 288], v);
  }
  // features
  int f = 0;
  for (int c=0; c<32; ++c){
    size_t ci = xb + ((size_t)c << 12);
    #pragma unroll
    for (int r=0; r<3; ++r){
      int hh = h + r - 1;
      bool rok = (unsigned)hh < 64u;
      #pragma unroll
      for (int dw=0; dw<3; ++dw){
        int ww = w + dw - 1;
        float v = (rok && (unsigned)ww < 64u) ? ld<BF>(x, ci + (hh<<6) + ww) : 0.f;
        #pragma unroll
        for (int s=0; s<6; ++s){
          float u = __shfl_up(v, 1 << s);
          v += same[s] ? u : 0.f;
        }
        if (tail) atomicAdd(&acc[k*289 + f], v);
        ++f;
      }
    }
  }
  __syncthreads();
  float* cp = cpart + (size_t)cg*(32*289);
  for (int e=t; e<32*289; e+=256) cp[e] = acc[e];
}

__global__ __launch_bounds__(256) void kC(const void* x, const int* idxg,
                                          float* cpart, const int* flag){
  __shared__ float acc[32*289];
  if (*flag) kC_body<true >(x, idxg, cpart, acc);
  else       kC_body<false>(x, idxg, cpart, acc);
}

// ---------------- Kernel D: merge partials -> centers + 2 MLPs + softmax ----------------
template<bool BF>
__device__ void kD_body(const float* __restrict__ cpart,
                        const void* kg_w1, const void* kg_b1,
                        const void* kg_w2, const void* kg_b2,
                        const void* kg_w3, const void* kg_b3,
                        const void* bg_w1, const void* bg_b1,
                        const void* bg_w2, const void* bg_b2,
                        const void* bg_w3, const void* bg_b3,
                        float* __restrict__ attn,
                        float* __restrict__ biasO,
                        float* __restrict__ row,
                        float* __restrict__ h1,
                        float* __restrict__ h2,
                        float* __restrict__ lgs){
  int wg = blockIdx.x; int b = wg >> 5; int k = wg & 31;
  int t = threadIdx.x;   // 64 threads
  float cnt = 0.f;
  for (int ch=0; ch<16; ++ch)
    cnt += cpart[((size_t)(b*16+ch)*32 + k)*289 + 288];
  float den = fmaxf(cnt, 1.f);
  for (int f=t; f<FF; f+=64){
    float s = 0.f;
    for (int ch=0; ch<16; ++ch)
      s += cpart[((size_t)(b*16+ch)*32 + k)*289 + f];
    row[f] = s / den;
  }
  __syncthreads();

  {
    float s = 0.f;
    #pragma unroll 8
    for (int f=0; f<FF; ++f) s = fmaf(row[f], ld<BF>(kg_w1, f*HID + t), s);
    h1[t] = fmaxf(s + ld<BF>(kg_b1, t), 0.f);
  }
  __syncthreads();
  {
    float s = 0.f;
    #pragma unroll 8
    for (int h=0; h<HID; ++h) s = fmaf(h1[h], ld<BF>(kg_w2, h*HID + t), s);
    h2[t] = fmaxf(s + ld<BF>(kg_b2, t), 0.f);
  }
  __syncthreads();
  if (t < 32){
    float s = 0.f;
    #pragma unroll 8
    for (int h=0; h<HID; ++h) s = fmaf(h2[h], ld<BF>(kg_w3, h*NBASE + t), s);
    lgs[t] = s + ld<BF>(kg_b3, t);
  }
  __syncthreads();
  if (t < 32){
    float mx = -3.0e38f;
    for (int i=0;i<NBASE;++i) mx = fmaxf(mx, lgs[i]);
    float se = 0.f;
    for (int i=0;i<NBASE;++i) se += expf(lgs[i]-mx);
    attn[wg*NBASE + t] = expf(lgs[t]-mx) / se;
  }
  __syncthreads();
  {
    float s = 0.f;
    #pragma unroll 8
    for (int f=0; f<FF; ++f) s = fmaf(row[f], ld<BF>(bg_w1, f*HID + t), s);
    h1[t] = fmaxf(s + ld<BF>(bg_b1, t), 0.f);
  }
  __syncthreads();
  {
    float s = 0.f;
    #pragma unroll 8
    for (int h=0; h<HID; ++h) s = fmaf(h1[h], ld<BF>(bg_w2, h*HID + t), s);
    h2[t] = fmaxf(s + ld<BF>(bg_b2, t), 0.f);
  }
  __syncthreads();
  {
    float s = 0.f;
    #pragma unroll 8
    for (int h=0; h<HID; ++h) s = fmaf(h1[h]*0.f + h2[h], ld<BF>(bg_w3, h*COUT + t), s);
    biasO[wg*COUT + t] = s + ld<BF>(bg_b3, t);
  }
}

__global__ __launch_bounds__(64) void kD(const float* cpart,
                                         const void* kg_w1, const void* kg_b1,
                                         const void* kg_w2, const void* kg_b2,
                                         const void* kg_w3, const void* kg_b3,
                                         const void* bg_w1, const void* bg_b1,
                                         const void* bg_w2, const void* bg_b2,
                                         const void* bg_w3, const void* bg_b3,
                                         float* attn, float* biasO, const int* flag){
  __shared__ float row[FF];
  __shared__ float h1[64];
  __shared__ float h2[64];
  __shared__ float lgs[32];
  if (*flag) kD_body<true >(cpart, kg_w1,kg_b1,kg_w2,kg_b2,kg_w3,kg_b3,
                            bg_w1,bg_b1,bg_w2,bg_b2,bg_w3,bg_b3, attn, biasO, row,h1,h2,lgs);
  else       kD_body<false>(cpart, kg_w1,kg_b1,kg_w2,kg_b2,kg_w3,kg_b3,
                            bg_w1,bg_b1,bg_w2,bg_b2,bg_w3,bg_b3, attn, biasO, row,h1,h2,lgs);
}

// ---------------- Kernel E: Wg[b][k][cout][f] (bf16) = sum_n attn*base ----------------
// grid 256: wg = (bk, f-quarter of 72). Compute read-coalesced, transpose in LDS,
// write coalesced bf16 rows.
template<bool BF>
__device__ void kE_body(const void* __restrict__ base,
                        const float* __restrict__ attn,
                        u16* __restrict__ Wg,
                        float* __restrict__ at,
                        float* __restrict__ tile){   // [72][65]
  int wg = blockIdx.x;
  int fq = wg & 3, bk = wg >> 2;
  int t = threadIdx.x;
  if (t < 32) at[t] = attn[bk*NBASE + t];
  __syncthreads();
  int f0 = fq*72;
  for (int e=t; e<72*64; e+=256){
    int fl = e >> 6, c = e & 63;
    size_t bi = (size_t)(f0 + fl)*COUT + c;
    float s = 0.f;
    #pragma unroll 8
    for (int n=0; n<NBASE; ++n)
      s = fmaf(at[n], ld<BF>(base, bi + (size_t)n*FF*COUT), s);
    tile[fl*65 + c] = s;
  }
  __syncthreads();
  for (int e=t; e<72*64; e+=256){
    int c = e / 72, fl = e % 72;
    Wg[(size_t)bk*(64*FF) + (size_t)c*FF + f0 + fl] = f2bf(tile[fl*65 + c]);
  }
}

__global__ __launch_bounds__(256) void kE(const void* base, const float* attn,
                                          u16* Wg, const int* flag){
  __shared__ float at[32];
  __shared__ float tile[72*65];
  if (*flag) kE_body<true >(base, attn, Wg, at, tile);
  else       kE_body<false>(base, attn, Wg, at, tile);
}

// ---------------- Kernel F: conv. wg = (b,h,quarter-row of 16 pts), grid 512 --------------
// phase1: patch rows f-linear bf16 in LDS [16][296]; phase2: wave=point, lane=cout:
// 36 x (uniform ds_read_b128 patch + 16B W row load) -> unpack -> fma;
// out to padded LDS tile [64][17]; phase3 coalesced stores.
template<bool BF>
__device__ void kF_body(const void* __restrict__ x,
                        const int* __restrict__ idxg,
                        const u16* __restrict__ Wg,
                        const float* __restrict__ biasO,
                        void* __restrict__ dout,
                        u16* __restrict__ patch,    // [16][296]
                        float* __restrict__ outT){  // [64][17]
  int wg = blockIdx.x;
  int q = wg & 3, h = (wg >> 2) & 63, b = wg >> 8;
  int t = threadIdx.x, wv = t >> 6, lane = t & 63;
  int w0 = q << 4;

  // phase1: patch[pl][f], f = c*9 + r*3 + dw
  for (int e=t; e<16*FF; e+=256){
    int pl = e & 15, fe = e >> 4;
    int c = fe / 9, j = fe % 9;
    int hh = h + j/3 - 1, ww = w0 + pl + (j%3) - 1;
    float v = 0.f;
    if ((unsigned)hh < 64u && (unsigned)ww < 64u)
      v = ld<BF>(x, ((size_t)b << 17) + ((size_t)c << 12) + (hh<<6) + ww);
    patch[pl*296 + fe] = f2bf(v);
  }
  __syncthreads();

  // phase2
  #pragma unroll
  for (int i=0; i<4; ++i){
    int pl = (wv << 2) + i;
    int p = (h << 6) + w0 + pl;
    int k = idxg[(b << 12) + p];
    const uint4* Wp = (const uint4*)(Wg + ((size_t)((b << 5) + k)*64 + lane)*FF);
    const uint4* Pp = (const uint4*)(patch + pl*296);
    float acc = 0.f;
    #pragma unroll 6
    for (int j=0; j<36; ++j){
      uint4 wv4 = Wp[j];
      uint4 pv4 = Pp[j];
      acc = fmaf(u_lo(pv4.x), u_lo(wv4.x), acc);
      acc = fmaf(u_hi(pv4.x), u_hi(wv4.x), acc);
      acc = fmaf(u_lo(pv4.y), u_lo(wv4.y), acc);
      acc = fmaf(u_hi(pv4.y), u_hi(wv4.y), acc);
      acc = fmaf(u_lo(pv4.z), u_lo(wv4.z), acc);
      acc = fmaf(u_hi(pv4.z), u_hi(wv4.z), acc);
      acc = fmaf(u_lo(pv4.w), u_lo(wv4.w), acc);
      acc = fmaf(u_hi(pv4.w), u_hi(wv4.w), acc);
    }
    float bias = biasO[((b << 5) + k)*COUT + lane];
    outT[lane*17 + pl] = acc + bias;
  }
  __syncthreads();

  // phase3: coalesced stores
  for (int e=t; e<1024; e+=256){
    int cout = e >> 4, pl = e & 15;
    st<BF>(dout, (((size_t)(b << 6) + cout) << 12) + (h << 6) + w0 + pl,
           outT[cout*17 + pl]);
  }
}

__global__ __launch_bounds__(256) void kF(const void* x, const int* idxg,
                                          const u16* Wg, const float* biasO,
                                          void* dout, const int* flag){
  __shared__ u16   patch[16*296];
  __shared__ float outT[64*17];
  if (*flag) kF_body<true >(x, idxg, Wg, biasO, dout, patch, outT);
  else       kF_body<false>(x, idxg, Wg, biasO, dout, patch, outT);
}

// ---------------- host: JAX threefry2x32 + permutation(key,4096)[:32] ----------------
static inline uint32_t rotl32(uint32_t x, int d){ return (x<<d)|(x>>(32-d)); }
static void tf_block(uint32_t k0,uint32_t k1,uint32_t x0,uint32_t x1,uint32_t&o0,uint32_t&o1){
  uint32_t ks2 = k0 ^ k1 ^ 0x1BD11BDAu;
  uint32_t v0 = x0 + k0, v1 = x1 + k1;
  const int ra[4]={13,15,26,6}, rb[4]={17,29,16,24};
  #define R4(r) for(int i_=0;i_<4;++i_){ v0 += v1; v1 = rotl32(v1,(r)[i_]); v1 ^= v0; }
  R4(ra); v0 += k1;  v1 += ks2 + 1u;
  R4(rb); v0 += ks2; v1 += k0  + 2u;
  R4(ra); v0 += k0;  v1 += k1  + 3u;
  R4(rb); v0 += k1;  v1 += ks2 + 4u;
  R4(ra); v0 += ks2; v1 += k0  + 5u;
  #undef R4
  o0 = v0; o1 = v1;
}
struct KP{ uint32_t a, b; };
static void tf_split(KP k, KP& first, KP& second){
#if THREEFRY_PARTITIONABLE
  uint32_t a0,b0,a1,b1;
  tf_block(k.a,k.b, 0u,0u, a0,b0);
  tf_block(k.a,k.b, 0u,1u, a1,b1);
  first  = KP{a0,b0};
  second = KP{a1,b1};
#else
  uint32_t a0,b0,a1,b1;
  tf_block(k.a,k.b, 0u,2u, a0,b0);
  tf_block(k.a,k.b, 1u,3u, a1,b1);
  first  = KP{a0,a1};
  second = KP{b0,b1};
#endif
}
static void random_bits_4096(KP k, std::vector<uint32_t>& bits){
#if THREEFRY_PARTITIONABLE
  for (int i=0;i<4096;++i){
    uint32_t o0,o1; tf_block(k.a,k.b, 0u,(uint32_t)i, o0,o1);
    bits[i] = o0 ^ o1;
  }
#else
  for (int i=0;i<2048;++i){
    uint32_t o0,o1; tf_block(k.a,k.b,(uint32_t)i,(uint32_t)(i+2048),o0,o1);
    bits[i] = o0; bits[i+2048] = o1;
  }
#endif
}
static void perm_first32(KP key, int* out32){
  std::vector<int> vals(4096);
  for (int i=0;i<4096;++i) vals[i] = i;
  std::vector<uint32_t> bits(4096);
  std::vector<std::pair<uint32_t,int>> pr(4096);
  KP k = key;
  for (int r=0;r<2;++r){
    KP nk, sk; tf_split(k, nk, sk); k = nk;
    random_bits_4096(sk, bits);
    for (int i=0;i<4096;++i) pr[i] = std::make_pair(bits[i], vals[i]);
    std::stable_sort(pr.begin(), pr.end(),
        [](const std::pair<uint32_t,int>& a, const std::pair<uint32_t,int>& c){ return a.first < c.first; });
    for (int i=0;i<4096;++i) vals[i] = pr[i].second;
  }
  for (int j=0;j<32;++j) out32[j] = vals[j];
}

extern "C" void kernel_launch(void* const* d_in, const int* in_sizes, int n_in,
                              void* d_out, int out_size, void* d_ws, size_t ws_size,
                              hipStream_t stream) {
  const void* x     = d_in[0];
  const void* base  = d_in[1];
  const void* kg_w1 = d_in[2];
  const void* kg_b1 = d_in[3];
  const void* kg_w2 = d_in[4];
  const void* kg_b2 = d_in[5];
  const void* kg_w3 = d_in[6];
  const void* kg_b3 = d_in[7];
  const void* bg_w1 = d_in[8];
  const void* bg_b1 = d_in[9];
  const void* bg_w2 = d_in[10];
  const void* bg_b2 = d_in[11];
  const void* bg_w3 = d_in[12];
  const void* bg_b3 = d_in[13];

  char* ws = (char*)d_ws;
  int*   bar   = (int*)ws;
  int*   flag  = (int*)(ws + 64);
  int*   idxg  = (int*)(ws + OFF_IDX);
  float* attn  = (float*)(ws + OFF_ATTN);
  float* biasO = (float*)(ws + OFF_BIAS);
  float* part  = (float*)(ws + OFF_PART);
  float* cpart = (float*)(ws + OFF_CPART);
  u16*   Wg    = (u16*)(ws + OFF_WG);

  InitIdx ii;
  KP root = KP{0u, 42u};
  KP kb0, kb1; tf_split(root, kb0, kb1);
  perm_first32(kb0, ii.v[0]);
  perm_first32(kb1, ii.v[1]);

  hipMemsetAsync(ws, 0, 64, stream);

  kDetect<<<1, 256, 0, stream>>>(x, flag);
  kB<<<NWG_KM, 256, 0, stream>>>(x, part, idxg, d_out, bar, flag, ii);
  kC<<<32, 256, 0, stream>>>(x, idxg, cpart, flag);
  kD<<<64, 64, 0, stream>>>(cpart,
                            kg_w1, kg_b1, kg_w2, kg_b2, kg_w3, kg_b3,
                            bg_w1, bg_b1, bg_w2, bg_b2, bg_w3, bg_b3,
                            attn, biasO, flag);
  kE<<<256, 256, 0, stream>>>(base, attn, Wg, flag);
  kF<<<512, 256, 0, stream>>>(x, idxg, Wg, biasO, d_out, flag);
}

// Round 8
// 386.487 us; speedup vs baseline: 1.6035x; 1.1292x over previous
//
#include <hip/hip_runtime.h>
#include <hip/hip_bf16.h>
#include <vector>
#include <algorithm>
#include <utility>
#include <stdint.h>

// Problem constants
#define BB 2
#define PP 4096        // H*W
#define FF 288         // C*9
#define KK 32
#define NBASE 32
#define HID 64
#define COUT 64
#define NWG_KM 32      // k-means workgroups (16 per batch)
#define SUBS 16
#define OUT_ELEMS 524288   // 2*64*4096; idx chunk follows

#define THREEFRY_PARTITIONABLE 1

typedef unsigned short u16;

// ---------------- ws layout (bytes) ----------------
// [0..63] barrier (memset 0), [64..67] dtype flag (written by kDetect)
#define OFF_IDX    512          // 2*4096*4  = 32768
#define OFF_ATTN   33280        // 64*32*4   = 8192
#define OFF_BIAS   41472        // 64*64*4   = 16384
#define OFF_PART   57856        // 64*1056*4 = 270336 -> 328192
#define OFF_CPART  328192       // 32 chunks * 32 k * 289 f32 = 1183744 -> 1511936
#define OFF_WG     1511936      // 64*64*288 u16 (b,k,cout,f) = 2359296 -> 3871232

struct InitIdx { int v[2][32]; };

// ---------------- device helpers ----------------
__device__ __forceinline__ float bf2f(u16 u){
  union { unsigned int i; float f; } cv; cv.i = ((unsigned int)u) << 16; return cv.f;
}
__device__ __forceinline__ u16 f2bf(float f){
  union { float f; unsigned int i; } cv; cv.f = f;
  unsigned int x = cv.i;
  unsigned int r = (x + 0x7FFFu + ((x >> 16) & 1u)) >> 16;
  return (u16)r;
}
__device__ __forceinline__ float u_lo(unsigned int u){
  union { unsigned int i; float f; } cv; cv.i = u << 16; return cv.f;
}
__device__ __forceinline__ float u_hi(unsigned int u){
  union { unsigned int i; float f; } cv; cv.i = u & 0xFFFF0000u; return cv.f;
}

template<bool BF>
__device__ __forceinline__ float ld(const void* p, size_t i){
  if constexpr (BF) { return bf2f(((const u16*)p)[i]); }
  else              { return ((const float*)p)[i]; }
}
template<bool BF>
__device__ __forceinline__ void st(void* p, size_t i, float v){
  if constexpr (BF) { ((u16*)p)[i] = f2bf(v); }
  else              { ((float*)p)[i] = v; }
}

template<bool BF>
__device__ __forceinline__ float obs_chan(const void* x, size_t bi, int h, int w){
  float s = 0.f;
  #pragma unroll
  for (int dh=-1; dh<=1; ++dh){
    int hh = h + dh;
    #pragma unroll
    for (int dw=-1; dw<=1; ++dw){
      int ww = w + dw;
      float v = 0.f;
      if ((unsigned)hh < 64u && (unsigned)ww < 64u) v = ld<BF>(x, bi + (hh<<6) + ww);
      s += v;
    }
  }
  return s / 9.0f;
}

__device__ __forceinline__ void gbar(int* cnt, int* gen, int nwg){
  __threadfence();
  __syncthreads();
  if (threadIdx.x == 0){
    int g = __hip_atomic_load(gen, __ATOMIC_RELAXED, __HIP_MEMORY_SCOPE_AGENT);
    int prev = __hip_atomic_fetch_add(cnt, 1, __ATOMIC_ACQ_REL, __HIP_MEMORY_SCOPE_AGENT);
    if (prev == nwg - 1){
      __hip_atomic_store(cnt, 0, __ATOMIC_RELAXED, __HIP_MEMORY_SCOPE_AGENT);
      __hip_atomic_fetch_add(gen, 1, __ATOMIC_RELEASE, __HIP_MEMORY_SCOPE_AGENT);
    } else {
      while (__hip_atomic_load(gen, __ATOMIC_ACQUIRE, __HIP_MEMORY_SCOPE_AGENT) == g){
        __builtin_amdgcn_s_sleep(2);
      }
    }
  }
  __syncthreads();
  __threadfence();
}

// ---------------- Kernel 0: input dtype detection (R5-verified) ----------------
__global__ __launch_bounds__(256) void kDetect(const void* __restrict__ x, int* flag){
  __shared__ int cnt;
  if (threadIdx.x == 0) cnt = 0;
  __syncthreads();
  const u16* p = (const u16*)x;
  int bad = 0;
  for (int i = threadIdx.x; i < 1024; i += 256){
    u16 u = p[2*i];
    unsigned e = (u >> 7) & 0xFFu;
    if (e >= 131u) ++bad;
  }
  atomicAdd(&cnt, bad);
  __syncthreads();
  if (threadIdx.x == 0) *flag = (cnt < 102) ? 1 : 0;
}

// ---------------- Kernel B: persistent k-means (semantics FROZEN, R5-verified) -------------
template<bool BF>
__device__ void kB_body(const void* __restrict__ x,
                        float* __restrict__ part,
                        int* __restrict__ idxg,
                        void* __restrict__ dout,
                        int* __restrict__ bar,
                        const InitIdx& ii){
  const int t   = threadIdx.x;
  const int wg  = blockIdx.x;
  const int mb  = wg >> 4;
  const int sub = wg & 15;
  const int pg  = sub*256 + t;

  __shared__ float obs_st[256][33];
  __shared__ float cent[2][32][32];
  __shared__ float cc_s[32];
  __shared__ int   a_loc[256];
  __shared__ float sq[32][32];
  __shared__ float snorm[32];
  __shared__ float cntsh[32];

  float o[32];
  {
    int h = pg >> 6, w = pg & 63;
    size_t xb = (size_t)mb << 17;
    for (int c=0; c<32; ++c){
      float v = obs_chan<BF>(x, xb + ((size_t)c<<12), h, w);
      o[c] = v; obs_st[t][c] = v;
    }
  }
  if (t < 64){
    int bb = t >> 5, j = t & 31;
    int q = ii.v[bb][j];
    int qh = q >> 6, qw = q & 63;
    size_t xq = (size_t)bb << 17;
    for (int c=0; c<32; ++c) cent[bb][j][c] = obs_chan<BF>(x, xq + ((size_t)c<<12), qh, qw);
  }
  __syncthreads();

  float ss = 0.f;
  #pragma unroll
  for (int d=0; d<32; ++d) ss = fmaf(o[d], o[d], ss);

  bool act0 = true, act1 = true;
  int parity = 0;

  for (int it=0; it<20; ++it){
    if (!(act0 || act1)) break;
    bool mine = (mb==0) ? act0 : act1;
    if (mine){
      if (t < 32){
        float s = 0.f;
        #pragma unroll
        for (int d=0; d<32; ++d){ float v = cent[mb][t][d]; s = fmaf(v,v,s); }
        cc_s[t] = s;
      }
      __syncthreads();
      float best = 3.0e38f; int bk = 0;
      for (int k=0; k<32; ++k){
        const float4* cr4 = (const float4*)&cent[mb][k][0];
        float dot = 0.f;
        #pragma unroll
        for (int d4=0; d4<8; ++d4){
          float4 c4 = cr4[d4];
          dot = fmaf(o[d4*4+0], c4.x, dot);
          dot = fmaf(o[d4*4+1], c4.y, dot);
          dot = fmaf(o[d4*4+2], c4.z, dot);
          dot = fmaf(o[d4*4+3], c4.w, dot);
        }
        float dist = (ss - 2.0f*dot) + cc_s[k];
        if (dist < best){ best = dist; bk = k; }
      }
      a_loc[t] = bk;
      __syncthreads();
      const int d = t & 31, g = t >> 5;
      float s0=0.f, s1=0.f, s2=0.f, s3=0.f;
      #pragma unroll 4
      for (int p=0; p<256; ++p){
        int ap = a_loc[p];
        float v = obs_st[p][d];
        s0 += (ap==g     ) ? v : 0.f;
        s1 += (ap==g + 8 ) ? v : 0.f;
        s2 += (ap==g + 16) ? v : 0.f;
        s3 += (ap==g + 24) ? v : 0.f;
      }
      float* Pg = part + ((size_t)((parity*2 + mb)*SUBS + sub))*1056;
      __hip_atomic_store(Pg + (g    )*33 + d, s0, __ATOMIC_RELAXED, __HIP_MEMORY_SCOPE_AGENT);
      __hip_atomic_store(Pg + (g+ 8 )*33 + d, s1, __ATOMIC_RELAXED, __HIP_MEMORY_SCOPE_AGENT);
      __hip_atomic_store(Pg + (g+16 )*33 + d, s2, __ATOMIC_RELAXED, __HIP_MEMORY_SCOPE_AGENT);
      __hip_atomic_store(Pg + (g+24 )*33 + d, s3, __ATOMIC_RELAXED, __HIP_MEMORY_SCOPE_AGENT);
      if (t < 32){
        int cnt_ = 0;
        #pragma unroll 4
        for (int p=0; p<256; ++p) cnt_ += (a_loc[p] == t) ? 1 : 0;
        __hip_atomic_store(Pg + t*33 + 32, (float)cnt_, __ATOMIC_RELAXED, __HIP_MEMORY_SCOPE_AGENT);
      }
    }
    gbar(bar, bar+1, NWG_KM);
    for (int bb=0; bb<2; ++bb){
      bool ab = (bb==0) ? act0 : act1;
      if (!ab) continue;
      const float* Pb = part + ((size_t)((parity*2 + bb)*SUBS))*1056;
      if (t < 32){
        float s = 0.f;
        for (int si=0; si<SUBS; ++si)
          s += __hip_atomic_load(Pb + (size_t)si*1056 + t*33 + 32, __ATOMIC_RELAXED, __HIP_MEMORY_SCOPE_AGENT);
        cntsh[t] = s;
      }
      __syncthreads();
      for (int e=t; e<1024; e+=256){
        int k = e >> 5, d = e & 31;
        float s = 0.f;
        for (int si=0; si<SUBS; ++si)
          s += __hip_atomic_load(Pb + (size_t)si*1056 + k*33 + d, __ATOMIC_RELAXED, __HIP_MEMORY_SCOPE_AGENT);
        float oldv = cent[bb][k][d];
        float cn = cntsh[k];
        float nv = (cn > 0.f) ? (s / fmaxf(cn, 1.f)) : oldv;
        float dd = nv - oldv;
        sq[k][d] = dd*dd;
        cent[bb][k][d] = nv;
      }
      __syncthreads();
      if (t < 32){
        float s = 0.f;
        #pragma unroll
        for (int d=0; d<32; ++d) s += sq[t][d];
        snorm[t] = sqrtf(s);
      }
      __syncthreads();
      float sh = 0.f;
      for (int k=0;k<32;++k) sh += snorm[k];
      bool na = ((it+1) < 20) && ((double)sh >= 20.48);
      if (bb==0) act0 = na; else act1 = na;
      __syncthreads();
    }
    parity ^= 1;
  }
  __syncthreads();
  if (t < 32){
    float s = 0.f;
    #pragma unroll
    for (int d=0; d<32; ++d){ float v = cent[mb][t][d]; s = fmaf(v,v,s); }
    cc_s[t] = s;
  }
  __syncthreads();
  float best = 3.0e38f; int bk = 0;
  for (int k=0; k<32; ++k){
    const float4* cr4 = (const float4*)&cent[mb][k][0];
    float dot = 0.f;
    #pragma unroll
    for (int d4=0; d4<8; ++d4){
      float4 c4 = cr4[d4];
      dot = fmaf(o[d4*4+0], c4.x, dot);
      dot = fmaf(o[d4*4+1], c4.y, dot);
      dot = fmaf(o[d4*4+2], c4.z, dot);
      dot = fmaf(o[d4*4+3], c4.w, dot);
    }
    float dist = (ss - 2.0f*dot) + cc_s[k];
    if (dist < best){ best = dist; bk = k; }
  }
  idxg[mb*PP + pg] = bk;
  st<BF>(dout, (size_t)OUT_ELEMS + mb*PP + pg, (float)bk);
}

__global__ __launch_bounds__(256) void kB(const void* x, float* part, int* idxg,
                                          void* dout, int* bar, const int* flag, InitIdx ii){
  if (*flag) kB_body<true >(x, part, idxg, dout, bar, ii);
  else       kB_body<false>(x, part, idxg, dout, bar, ii);
}

// ---------------- Kernel C v4: run-accumulated cluster patch sums (CHANGE UNDER TEST) ------
// grid 32: wg = (b, chunk of 256 points = 4 rows). Waves partition features
// (wave wv owns f in [72wv,72wv+72)); lanes own 1-2 fixed features. Iterate the
// 256 points serially, accumulating in a register while the (wave-uniform)
// cluster id is unchanged; flush to LDS at run boundaries. Each acc cell is
// owned by exactly one lane: no atomics on features, no conflicts, deterministic.
template<bool BF>
__device__ void kC_body(const void* __restrict__ x,
                        const int* __restrict__ idxg,
                        float* __restrict__ cpart,
                        float* __restrict__ acc,    // [32*289]
                        int* __restrict__ icnt,     // [32]
                        int* __restrict__ idxsh){   // [256]
  int cg = blockIdx.x;            // 0..31
  int b = cg >> 4, pc = cg & 15;
  int t = threadIdx.x, wv = t >> 6, lane = t & 63;
  for (int e=t; e<32*289; e+=256) acc[e] = 0.f;
  if (t < 32) icnt[t] = 0;
  idxsh[t] = idxg[b*PP + pc*256 + t];
  __syncthreads();
  atomicAdd(&icnt[idxsh[t]], 1);

  int f0 = wv*72 + lane;
  int f1 = wv*72 + 64 + lane;
  bool has1 = lane < 8;
  int c0 = f0/9, j0 = f0%9, dh0 = j0/3 - 1, dw0 = j0%3 - 1;
  int c1 = f1/9, j1 = f1%9, dh1 = j1/3 - 1, dw1 = j1%3 - 1;
  size_t xb = (size_t)b << 17;

  float v0 = 0.f, v1 = 0.f; int kcur = -1;
  for (int i=0; i<256; ++i){
    int k = idxsh[i];
    if (k != kcur){
      if (kcur >= 0){
        acc[kcur*289 + f0] += v0;
        if (has1) acc[kcur*289 + f1] += v1;
      }
      v0 = 0.f; v1 = 0.f; kcur = k;
    }
    int h = (pc << 2) + (i >> 6), w_ = i & 63;
    int hh0 = h + dh0, ww0 = w_ + dw0;
    if ((unsigned)hh0 < 64u && (unsigned)ww0 < 64u)
      v0 += ld<BF>(x, xb + ((size_t)c0 << 12) + (hh0 << 6) + ww0);
    if (has1){
      int hh1 = h + dh1, ww1 = w_ + dw1;
      if ((unsigned)hh1 < 64u && (unsigned)ww1 < 64u)
        v1 += ld<BF>(x, xb + ((size_t)c1 << 12) + (hh1 << 6) + ww1);
    }
  }
  acc[kcur*289 + f0] += v0;
  if (has1) acc[kcur*289 + f1] += v1;
  __syncthreads();
  float* cp = cpart + (size_t)cg*(32*289);
  for (int e=t; e<32*289; e+=256){
    int r = e % 289;
    cp[e] = (r == 288) ? (float)icnt[e/289] : acc[e];
  }
}

__global__ __launch_bounds__(256) void kC(const void* x, const int* idxg,
                                          float* cpart, const int* flag){
  __shared__ float acc[32*289];
  __shared__ int   icnt[32];
  __shared__ int   idxsh[256];
  if (*flag) kC_body<true >(x, idxg, cpart, acc, icnt, idxsh);
  else       kC_body<false>(x, idxg, cpart, acc, icnt, idxsh);
}

// ---------------- Kernel D: merge partials -> centers + 2 MLPs + softmax (R5-verified) -----
template<bool BF>
__device__ void kD_body(const float* __restrict__ cpart,
                        const void* kg_w1, const void* kg_b1,
                        const void* kg_w2, const void* kg_b2,
                        const void* kg_w3, const void* kg_b3,
                        const void* bg_w1, const void* bg_b1,
                        const void* bg_w2, const void* bg_b2,
                        const void* bg_w3, const void* bg_b3,
                        float* __restrict__ attn,
                        float* __restrict__ biasO,
                        float* __restrict__ row,
                        float* __restrict__ h1,
                        float* __restrict__ h2,
                        float* __restrict__ lgs){
  int wg = blockIdx.x; int b = wg >> 5; int k = wg & 31;
  int t = threadIdx.x;   // 64 threads
  float cnt = 0.f;
  for (int ch=0; ch<16; ++ch)
    cnt += cpart[((size_t)(b*16+ch)*32 + k)*289 + 288];
  float den = fmaxf(cnt, 1.f);
  for (int f=t; f<FF; f+=64){
    float s = 0.f;
    for (int ch=0; ch<16; ++ch)
      s += cpart[((size_t)(b*16+ch)*32 + k)*289 + f];
    row[f] = s / den;
  }
  __syncthreads();

  {
    float s = 0.f;
    #pragma unroll 8
    for (int f=0; f<FF; ++f) s = fmaf(row[f], ld<BF>(kg_w1, f*HID + t), s);
    h1[t] = fmaxf(s + ld<BF>(kg_b1, t), 0.f);
  }
  __syncthreads();
  {
    float s = 0.f;
    #pragma unroll 8
    for (int h=0; h<HID; ++h) s = fmaf(h1[h], ld<BF>(kg_w2, h*HID + t), s);
    h2[t] = fmaxf(s + ld<BF>(kg_b2, t), 0.f);
  }
  __syncthreads();
  if (t < 32){
    float s = 0.f;
    #pragma unroll 8
    for (int h=0; h<HID; ++h) s = fmaf(h2[h], ld<BF>(kg_w3, h*NBASE + t), s);
    lgs[t] = s + ld<BF>(kg_b3, t);
  }
  __syncthreads();
  if (t < 32){
    float mx = -3.0e38f;
    for (int i=0;i<NBASE;++i) mx = fmaxf(mx, lgs[i]);
    float se = 0.f;
    for (int i=0;i<NBASE;++i) se += expf(lgs[i]-mx);
    attn[wg*NBASE + t] = expf(lgs[t]-mx) / se;
  }
  __syncthreads();
  {
    float s = 0.f;
    #pragma unroll 8
    for (int f=0; f<FF; ++f) s = fmaf(row[f], ld<BF>(bg_w1, f*HID + t), s);
    h1[t] = fmaxf(s + ld<BF>(bg_b1, t), 0.f);
  }
  __syncthreads();
  {
    float s = 0.f;
    #pragma unroll 8
    for (int h=0; h<HID; ++h) s = fmaf(h1[h], ld<BF>(bg_w2, h*HID + t), s);
    h2[t] = fmaxf(s + ld<BF>(bg_b2, t), 0.f);
  }
  __syncthreads();
  {
    float s = 0.f;
    #pragma unroll 8
    for (int h=0; h<HID; ++h) s = fmaf(h2[h], ld<BF>(bg_w3, h*COUT + t), s);
    biasO[wg*COUT + t] = s + ld<BF>(bg_b3, t);
  }
}

__global__ __launch_bounds__(64) void kD(const float* cpart,
                                         const void* kg_w1, const void* kg_b1,
                                         const void* kg_w2, const void* kg_b2,
                                         const void* kg_w3, const void* kg_b3,
                                         const void* bg_w1, const void* bg_b1,
                                         const void* bg_w2, const void* bg_b2,
                                         const void* bg_w3, const void* bg_b3,
                                         float* attn, float* biasO, const int* flag){
  __shared__ float row[FF];
  __shared__ float h1[64];
  __shared__ float h2[64];
  __shared__ float lgs[32];
  if (*flag) kD_body<true >(cpart, kg_w1,kg_b1,kg_w2,kg_b2,kg_w3,kg_b3,
                            bg_w1,bg_b1,bg_w2,bg_b2,bg_w3,bg_b3, attn, biasO, row,h1,h2,lgs);
  else       kD_body<false>(cpart, kg_w1,kg_b1,kg_w2,kg_b2,kg_w3,kg_b3,
                            bg_w1,bg_b1,bg_w2,bg_b2,bg_w3,bg_b3, attn, biasO, row,h1,h2,lgs);
}

// ---------------- Kernel E: Wg[b][k][cout][f] (bf16) = sum_n attn*base (R5-verified) -------
template<bool BF>
__device__ void kE_body(const void* __restrict__ base,
                        const float* __restrict__ attn,
                        u16* __restrict__ Wg,
                        float* __restrict__ at,
                        float* __restrict__ tile){   // [72][65]
  int wg = blockIdx.x;
  int fq = wg & 3, bk = wg >> 2;
  int t = threadIdx.x;
  if (t < 32) at[t] = attn[bk*NBASE + t];
  __syncthreads();
  int f0 = fq*72;
  for (int e=t; e<72*64; e+=256){
    int fl = e >> 6, c = e & 63;
    size_t bi = (size_t)(f0 + fl)*COUT + c;
    float s = 0.f;
    #pragma unroll 8
    for (int n=0; n<NBASE; ++n)
      s = fmaf(at[n], ld<BF>(base, bi + (size_t)n*FF*COUT), s);
    tile[fl*65 + c] = s;
  }
  __syncthreads();
  for (int e=t; e<72*64; e+=256){
    int c = e / 72, fl = e % 72;
    Wg[(size_t)bk*(64*FF) + (size_t)c*FF + f0 + fl] = f2bf(tile[fl*65 + c]);
  }
}

__global__ __launch_bounds__(256) void kE(const void* base, const float* attn,
                                          u16* Wg, const int* flag){
  __shared__ float at[32];
  __shared__ float tile[72*65];
  if (*flag) kE_body<true >(base, attn, Wg, at, tile);
  else       kE_body<false>(base, attn, Wg, at, tile);
}

// ---------------- Kernel F: conv (R5 structure, verified) ----------------
template<bool BF>
__device__ void kF_body(const void* __restrict__ x,
                        const int* __restrict__ idxg,
                        const u16* __restrict__ Wg,
                        const float* __restrict__ biasO,
                        void* __restrict__ dout,
                        u16* __restrict__ patch,    // [16][296]
                        float* __restrict__ outT){  // [64][17]
  int wg = blockIdx.x;
  int q = wg & 3, h = (wg >> 2) & 63, b = wg >> 8;
  int t = threadIdx.x, wv = t >> 6, lane = t & 63;
  int w0 = q << 4;

  for (int e=t; e<16*FF; e+=256){
    int pl = e & 15, fe = e >> 4;
    int c = fe / 9, j = fe % 9;
    int hh = h + j/3 - 1, ww = w0 + pl + (j%3) - 1;
    float v = 0.f;
    if ((unsigned)hh < 64u && (unsigned)ww < 64u)
      v = ld<BF>(x, ((size_t)b << 17) + ((size_t)c << 12) + (hh<<6) + ww);
    patch[pl*296 + fe] = f2bf(v);
  }
  __syncthreads();

  #pragma unroll
  for (int i=0; i<4; ++i){
    int pl = (wv << 2) + i;
    int p = (h << 6) + w0 + pl;
    int k = idxg[(b << 12) + p];
    const uint4* Wp = (const uint4*)(Wg + ((size_t)((b << 5) + k)*64 + lane)*FF);
    const uint4* Pp = (const uint4*)(patch + pl*296);
    float acc = 0.f;
    #pragma unroll 6
    for (int j=0; j<36; ++j){
      uint4 wv4 = Wp[j];
      uint4 pv4 = Pp[j];
      acc = fmaf(u_lo(pv4.x), u_lo(wv4.x), acc);
      acc = fmaf(u_hi(pv4.x), u_hi(wv4.x), acc);
      acc = fmaf(u_lo(pv4.y), u_lo(wv4.y), acc);
      acc = fmaf(u_hi(pv4.y), u_hi(wv4.y), acc);
      acc = fmaf(u_lo(pv4.z), u_lo(wv4.z), acc);
      acc = fmaf(u_hi(pv4.z), u_hi(wv4.z), acc);
      acc = fmaf(u_lo(pv4.w), u_lo(wv4.w), acc);
      acc = fmaf(u_hi(pv4.w), u_hi(wv4.w), acc);
    }
    float bias = biasO[((b << 5) + k)*COUT + lane];
    outT[lane*17 + pl] = acc + bias;
  }
  __syncthreads();

  for (int e=t; e<1024; e+=256){
    int cout = e >> 4, pl = e & 15;
    st<BF>(dout, (((size_t)(b << 6) + cout) << 12) + (h << 6) + w0 + pl,
           outT[cout*17 + pl]);
  }
}

__global__ __launch_bounds__(256) void kF(const void* x, const int* idxg,
                                          const u16* Wg, const float* biasO,
                                          void* dout, const int* flag){
  __shared__ u16   patch[16*296];
  __shared__ float outT[64*17];
  if (*flag) kF_body<true >(x, idxg, Wg, biasO, dout, patch, outT);
  else       kF_body<false>(x, idxg, Wg, biasO, dout, patch, outT);
}

// ---------------- host: JAX threefry2x32 + permutation(key,4096)[:32] ----------------
static inline uint32_t rotl32(uint32_t x, int d){ return (x<<d)|(x>>(32-d)); }
static void tf_block(uint32_t k0,uint32_t k1,uint32_t x0,uint32_t x1,uint32_t&o0,uint32_t&o1){
  uint32_t ks2 = k0 ^ k1 ^ 0x1BD11BDAu;
  uint32_t v0 = x0 + k0, v1 = x1 + k1;
  const int ra[4]={13,15,26,6}, rb[4]={17,29,16,24};
  #define R4(r) for(int i_=0;i_<4;++i_){ v0 += v1; v1 = rotl32(v1,(r)[i_]); v1 ^= v0; }
  R4(ra); v0 += k1;  v1 += ks2 + 1u;
  R4(rb); v0 += ks2; v1 += k0  + 2u;
  R4(ra); v0 += k0;  v1 += k1  + 3u;
  R4(rb); v0 += k1;  v1 += ks2 + 4u;
  R4(ra); v0 += ks2; v1 += k0  + 5u;
  #undef R4
  o0 = v0; o1 = v1;
}
struct KP{ uint32_t a, b; };
static void tf_split(KP k, KP& first, KP& second){
#if THREEFRY_PARTITIONABLE
  uint32_t a0,b0,a1,b1;
  tf_block(k.a,k.b, 0u,0u, a0,b0);
  tf_block(k.a,k.b, 0u,1u, a1,b1);
  first  = KP{a0,b0};
  second = KP{a1,b1};
#else
  uint32_t a0,b0,a1,b1;
  tf_block(k.a,k.b, 0u,2u, a0,b0);
  tf_block(k.a,k.b, 1u,3u, a1,b1);
  first  = KP{a0,a1};
  second = KP{b0,b1};
#endif
}
static void random_bits_4096(KP k, std::vector<uint32_t>& bits){
#if THREEFRY_PARTITIONABLE
  for (int i=0;i<4096;++i){
    uint32_t o0,o1; tf_block(k.a,k.b, 0u,(uint32_t)i, o0,o1);
    bits[i] = o0 ^ o1;
  }
#else
  for (int i=0;i<2048;++i){
    uint32_t o0,o1; tf_block(k.a,k.b,(uint32_t)i,(uint32_t)(i+2048),o0,o1);
    bits[i] = o0; bits[i+2048] = o1;
  }
#endif
}
static void perm_first32(KP key, int* out32){
  std::vector<int> vals(4096);
  for (int i=0;i<4096;++i) vals[i] = i;
  std::vector<uint32_t> bits(4096);
  std::vector<std::pair<uint32_t,int>> pr(4096);
  KP k = key;
  for (int r=0;r<2;++r){
    KP nk, sk; tf_split(k, nk, sk); k = nk;
    random_bits_4096(sk, bits);
    for (int i=0;i<4096;++i) pr[i] = std::make_pair(bits[i], vals[i]);
    std::stable_sort(pr.begin(), pr.end(),
        [](const std::pair<uint32_t,int>& a, const std::pair<uint32_t,int>& c){ return a.first < c.first; });
    for (int i=0;i<4096;++i) vals[i] = pr[i].second;
  }
  for (int j=0;j<32;++j) out32[j] = vals[j];
}

extern "C" void kernel_launch(void* const* d_in, const int* in_sizes, int n_in,
                              void* d_out, int out_size, void* d_ws, size_t ws_size,
                              hipStream_t stream) {
  const void* x     = d_in[0];
  const void* base  = d_in[1];
  const void* kg_w1 = d_in[2];
  const void* kg_b1 = d_in[3];
  const void* kg_w2 = d_in[4];
  const void* kg_b2 = d_in[5];
  const void* kg_w3 = d_in[6];
  const void* kg_b3 = d_in[7];
  const void* bg_w1 = d_in[8];
  const void* bg_b1 = d_in[9];
  const void* bg_w2 = d_in[10];
  const void* bg_b2 = d_in[11];
  const void* bg_w3 = d_in[12];
  const void* bg_b3 = d_in[13];

  char* ws = (char*)d_ws;
  int*   bar   = (int*)ws;
  int*   flag  = (int*)(ws + 64);
  int*   idxg  = (int*)(ws + OFF_IDX);
  float* attn  = (float*)(ws + OFF_ATTN);
  float* biasO = (float*)(ws + OFF_BIAS);
  float* part  = (float*)(ws + OFF_PART);
  float* cpart = (float*)(ws + OFF_CPART);
  u16*   Wg    = (u16*)(ws + OFF_WG);

  InitIdx ii;
  KP root = KP{0u, 42u};
  KP kb0, kb1; tf_split(root, kb0, kb1);
  perm_first32(kb0, ii.v[0]);
  perm_first32(kb1, ii.v[1]);

  hipMemsetAsync(ws, 0, 64, stream);

  kDetect<<<1, 256, 0, stream>>>(x, flag);
  kB<<<NWG_KM, 256, 0, stream>>>(x, part, idxg, d_out, bar, flag, ii);
  kC<<<32, 256, 0, stream>>>(x, idxg, cpart, flag);
  kD<<<64, 64, 0, stream>>>(cpart,
                            kg_w1, kg_b1, kg_w2, kg_b2, kg_w3, kg_b3,
                            bg_w1, bg_b1, bg_w2, bg_b2, bg_w3, bg_b3,
                            attn, biasO, flag);
  kE<<<256, 256, 0, stream>>>(base, attn, Wg, flag);
  kF<<<512, 256, 0, stream>>>(x, idxg, Wg, biasO, d_out, flag);
}

// Round 9
// 382.922 us; speedup vs baseline: 1.6185x; 1.0093x over previous
//
#include <hip/hip_runtime.h>
#include <hip/hip_bf16.h>
#include <vector>
#include <algorithm>
#include <utility>
#include <stdint.h>

// Problem constants
#define BB 2
#define PP 4096        // H*W
#define FF 288         // C*9
#define KK 32
#define NBASE 32
#define HID 64
#define COUT 64
#define NWG_KM 32      // k-means workgroups (16 per batch)
#define SUBS 16
#define OUT_ELEMS 524288   // 2*64*4096; idx chunk follows

#define THREEFRY_PARTITIONABLE 1

typedef unsigned short u16;

// ---------------- ws layout (bytes) ----------------
// [64..67] dtype flag (written by kDetect)
#define OFF_IDX    512          // 2*4096*4  = 32768
#define OFF_ATTN   33280        // 64*32*4   = 8192
#define OFF_BIAS   41472        // 64*64*4   = 16384
#define OFF_PART   57856        // 4 slots * 16 subs * 1024 f32 = 262144 -> 320000
#define OFF_CNTS   320000       // 4 slots * 16 subs * 32 f32   = 8192   -> 328192
#define OFF_CPART  328192       // 32 chunks * 32 k * 289 f32 = 1183744 -> 1511936
#define OFF_WG     1511936      // 64*64*288 u16 (b,k,cout,f) = 2359296 -> 3871232
#define OFF_BAR2   3871232      // slots 32*16 ints (2048) + gen (4); memset 4096

struct InitIdx { int v[2][32]; };

// ---------------- device helpers ----------------
__device__ __forceinline__ float bf2f(u16 u){
  union { unsigned int i; float f; } cv; cv.i = ((unsigned int)u) << 16; return cv.f;
}
__device__ __forceinline__ u16 f2bf(float f){
  union { float f; unsigned int i; } cv; cv.f = f;
  unsigned int x = cv.i;
  unsigned int r = (x + 0x7FFFu + ((x >> 16) & 1u)) >> 16;
  return (u16)r;
}
__device__ __forceinline__ float u_lo(unsigned int u){
  union { unsigned int i; float f; } cv; cv.i = u << 16; return cv.f;
}
__device__ __forceinline__ float u_hi(unsigned int u){
  union { unsigned int i; float f; } cv; cv.i = u & 0xFFFF0000u; return cv.f;
}

template<bool BF>
__device__ __forceinline__ float ld(const void* p, size_t i){
  if constexpr (BF) { return bf2f(((const u16*)p)[i]); }
  else              { return ((const float*)p)[i]; }
}
template<bool BF>
__device__ __forceinline__ void st(void* p, size_t i, float v){
  if constexpr (BF) { ((u16*)p)[i] = f2bf(v); }
  else              { ((float*)p)[i] = v; }
}

template<bool BF>
__device__ __forceinline__ float obs_chan(const void* x, size_t bi, int h, int w){
  float s = 0.f;
  #pragma unroll
  for (int dh=-1; dh<=1; ++dh){
    int hh = h + dh;
    #pragma unroll
    for (int dw=-1; dw<=1; ++dw){
      int ww = w + dw;
      float v = 0.f;
      if ((unsigned)hh < 64u && (unsigned)ww < 64u) v = ld<BF>(x, bi + (hh<<6) + ww);
      s += v;
    }
  }
  return s / 9.0f;
}

// Flag-tree grid barrier: wg i stores epoch to its own cacheline slot (no RMW);
// wg0 lanes poll all slots in parallel, then release gen; everyone polls gen.
__device__ __forceinline__ void gbar2(int* slots, int* gen, int nwg, int epoch){
  __syncthreads();
  __threadfence();
  const int t = threadIdx.x;
  const int wg = blockIdx.x;
  if (t == 0)
    __hip_atomic_store(&slots[wg*16], epoch, __ATOMIC_RELEASE, __HIP_MEMORY_SCOPE_AGENT);
  if (wg == 0){
    if (t < nwg){
      while (__hip_atomic_load(&slots[t*16], __ATOMIC_ACQUIRE, __HIP_MEMORY_SCOPE_AGENT) < epoch){}
    }
    __syncthreads();
    if (t == 0)
      __hip_atomic_store(gen, epoch, __ATOMIC_RELEASE, __HIP_MEMORY_SCOPE_AGENT);
  }
  if (t == 0){
    while (__hip_atomic_load(gen, __ATOMIC_ACQUIRE, __HIP_MEMORY_SCOPE_AGENT) < epoch){}
  }
  __syncthreads();
  __threadfence();
}

// ---------------- Kernel 0: input dtype detection (verified) ----------------
__global__ __launch_bounds__(256) void kDetect(const void* __restrict__ x, int* flag){
  __shared__ int cnt;
  if (threadIdx.x == 0) cnt = 0;
  __syncthreads();
  const u16* p = (const u16*)x;
  int bad = 0;
  for (int i = threadIdx.x; i < 1024; i += 256){
    u16 u = p[2*i];
    unsigned e = (u >> 7) & 0xFFu;
    if (e >= 131u) ++bad;
  }
  atomicAdd(&cnt, bad);
  __syncthreads();
  if (threadIdx.x == 0) *flag = (cnt < 102) ? 1 : 0;
}

// ---------------- Kernel B: persistent k-means (idx semantics FROZEN) ----------------
// Change under test: flag-tree barrier + float4 partial merge (plain ld/st).
template<bool BF>
__device__ void kB_body(const void* __restrict__ x,
                        float* __restrict__ part,
                        float* __restrict__ cnts,
                        int* __restrict__ idxg,
                        void* __restrict__ dout,
                        int* __restrict__ slots,
                        int* __restrict__ gen,
                        const InitIdx& ii){
  const int t   = threadIdx.x;
  const int wg  = blockIdx.x;
  const int mb  = wg >> 4;
  const int sub = wg & 15;
  const int pg  = sub*256 + t;

  __shared__ float obs_st[256][33];
  __shared__ float cent[2][32][32];
  __shared__ float cc_s[32];
  __shared__ int   a_loc[256];
  __shared__ float sq[32][32];
  __shared__ float snorm[32];
  __shared__ float cntsh[32];

  float o[32];
  {
    int h = pg >> 6, w = pg & 63;
    size_t xb = (size_t)mb << 17;
    for (int c=0; c<32; ++c){
      float v = obs_chan<BF>(x, xb + ((size_t)c<<12), h, w);
      o[c] = v; obs_st[t][c] = v;
    }
  }
  if (t < 64){
    int bb = t >> 5, j = t & 31;
    int q = ii.v[bb][j];
    int qh = q >> 6, qw = q & 63;
    size_t xq = (size_t)bb << 17;
    for (int c=0; c<32; ++c) cent[bb][j][c] = obs_chan<BF>(x, xq + ((size_t)c<<12), qh, qw);
  }
  __syncthreads();

  float ss = 0.f;
  #pragma unroll
  for (int d=0; d<32; ++d) ss = fmaf(o[d], o[d], ss);

  bool act0 = true, act1 = true;
  int parity = 0;

  for (int it=0; it<20; ++it){
    if (!(act0 || act1)) break;
    bool mine = (mb==0) ? act0 : act1;
    if (mine){
      if (t < 32){
        float s = 0.f;
        #pragma unroll
        for (int d=0; d<32; ++d){ float v = cent[mb][t][d]; s = fmaf(v,v,s); }
        cc_s[t] = s;
      }
      __syncthreads();
      float best = 3.0e38f; int bk = 0;
      for (int k=0; k<32; ++k){
        const float4* cr4 = (const float4*)&cent[mb][k][0];
        float dot = 0.f;
        #pragma unroll
        for (int d4=0; d4<8; ++d4){
          float4 c4 = cr4[d4];
          dot = fmaf(o[d4*4+0], c4.x, dot);
          dot = fmaf(o[d4*4+1], c4.y, dot);
          dot = fmaf(o[d4*4+2], c4.z, dot);
          dot = fmaf(o[d4*4+3], c4.w, dot);
        }
        float dist = (ss - 2.0f*dot) + cc_s[k];
        if (dist < best){ best = dist; bk = k; }
      }
      a_loc[t] = bk;
      __syncthreads();
      const int d = t & 31, g = t >> 5;
      float s0=0.f, s1=0.f, s2=0.f, s3=0.f;
      #pragma unroll 4
      for (int p=0; p<256; ++p){
        int ap = a_loc[p];
        float v = obs_st[p][d];
        s0 += (ap==g     ) ? v : 0.f;
        s1 += (ap==g + 8 ) ? v : 0.f;
        s2 += (ap==g + 16) ? v : 0.f;
        s3 += (ap==g + 24) ? v : 0.f;
      }
      float* Pg = part + ((size_t)((parity*2 + mb)*SUBS + sub))*1024;
      Pg[(g    )*32 + d] = s0;
      Pg[(g+ 8 )*32 + d] = s1;
      Pg[(g+16 )*32 + d] = s2;
      Pg[(g+24 )*32 + d] = s3;
      if (t < 32){
        int cnt_ = 0;
        #pragma unroll 4
        for (int p=0; p<256; ++p) cnt_ += (a_loc[p] == t) ? 1 : 0;
        cnts[((size_t)((parity*2 + mb)*SUBS + sub))*32 + t] = (float)cnt_;
      }
    }
    gbar2(slots, gen, NWG_KM, it+1);
    for (int bb=0; bb<2; ++bb){
      bool ab = (bb==0) ? act0 : act1;
      if (!ab) continue;
      const float* Pb = part + (size_t)((parity*2 + bb)*SUBS)*1024;
      const float* Cb = cnts + (size_t)((parity*2 + bb)*SUBS)*32;
      if (t < 32){
        float s = 0.f;
        for (int si=0; si<SUBS; ++si) s += Cb[si*32 + t];
        cntsh[t] = s;
      }
      __syncthreads();
      {
        int k = t >> 3, d4 = (t & 7) * 4;
        float4 v = make_float4(0.f, 0.f, 0.f, 0.f);
        for (int si=0; si<SUBS; ++si){
          const float4 p4 = *(const float4*)&Pb[si*1024 + k*32 + d4];
          v.x += p4.x; v.y += p4.y; v.z += p4.z; v.w += p4.w;
        }
        float cn = cntsh[k];
        float den = fmaxf(cn, 1.f);
        bool pos = cn > 0.f;
        float o0 = cent[bb][k][d4+0], o1 = cent[bb][k][d4+1];
        float o2 = cent[bb][k][d4+2], o3 = cent[bb][k][d4+3];
        float n0 = pos ? (v.x / den) : o0;
        float n1 = pos ? (v.y / den) : o1;
        float n2 = pos ? (v.z / den) : o2;
        float n3 = pos ? (v.w / den) : o3;
        float e0 = n0-o0, e1 = n1-o1, e2 = n2-o2, e3 = n3-o3;
        sq[k][d4+0] = e0*e0; sq[k][d4+1] = e1*e1;
        sq[k][d4+2] = e2*e2; sq[k][d4+3] = e3*e3;
        cent[bb][k][d4+0] = n0; cent[bb][k][d4+1] = n1;
        cent[bb][k][d4+2] = n2; cent[bb][k][d4+3] = n3;
      }
      __syncthreads();
      if (t < 32){
        float s = 0.f;
        #pragma unroll
        for (int d=0; d<32; ++d) s += sq[t][d];
        snorm[t] = sqrtf(s);
      }
      __syncthreads();
      float sh = 0.f;
      for (int k=0;k<32;++k) sh += snorm[k];
      bool na = ((it+1) < 20) && ((double)sh >= 20.48);
      if (bb==0) act0 = na; else act1 = na;
      __syncthreads();
    }
    parity ^= 1;
  }
  __syncthreads();
  if (t < 32){
    float s = 0.f;
    #pragma unroll
    for (int d=0; d<32; ++d){ float v = cent[mb][t][d]; s = fmaf(v,v,s); }
    cc_s[t] = s;
  }
  __syncthreads();
  float best = 3.0e38f; int bk = 0;
  for (int k=0; k<32; ++k){
    const float4* cr4 = (const float4*)&cent[mb][k][0];
    float dot = 0.f;
    #pragma unroll
    for (int d4=0; d4<8; ++d4){
      float4 c4 = cr4[d4];
      dot = fmaf(o[d4*4+0], c4.x, dot);
      dot = fmaf(o[d4*4+1], c4.y, dot);
      dot = fmaf(o[d4*4+2], c4.z, dot);
      dot = fmaf(o[d4*4+3], c4.w, dot);
    }
    float dist = (ss - 2.0f*dot) + cc_s[k];
    if (dist < best){ best = dist; bk = k; }
  }
  idxg[mb*PP + pg] = bk;
  st<BF>(dout, (size_t)OUT_ELEMS + mb*PP + pg, (float)bk);
}

__global__ __launch_bounds__(256) void kB(const void* x, float* part, float* cnts,
                                          int* idxg, void* dout,
                                          int* slots, int* gen,
                                          const int* flag, InitIdx ii){
  if (*flag) kB_body<true >(x, part, cnts, idxg, dout, slots, gen, ii);
  else       kB_body<false>(x, part, cnts, idxg, dout, slots, gen, ii);
}

// ---------------- Kernel C v4: run-accumulated cluster patch sums (R8-verified) ------------
template<bool BF>
__device__ void kC_body(const void* __restrict__ x,
                        const int* __restrict__ idxg,
                        float* __restrict__ cpart,
                        float* __restrict__ acc,    // [32*289]
                        int* __restrict__ icnt,     // [32]
                        int* __restrict__ idxsh){   // [256]
  int cg = blockIdx.x;            // 0..31
  int b = cg >> 4, pc = cg & 15;
  int t = threadIdx.x, wv = t >> 6, lane = t & 63;
  for (int e=t; e<32*289; e+=256) acc[e] = 0.f;
  if (t < 32) icnt[t] = 0;
  idxsh[t] = idxg[b*PP + pc*256 + t];
  __syncthreads();
  atomicAdd(&icnt[idxsh[t]], 1);

  int f0 = wv*72 + lane;
  int f1 = wv*72 + 64 + lane;
  bool has1 = lane < 8;
  int c0 = f0/9, j0 = f0%9, dh0 = j0/3 - 1, dw0 = j0%3 - 1;
  int c1 = f1/9, j1 = f1%9, dh1 = j1/3 - 1, dw1 = j1%3 - 1;
  size_t xb = (size_t)b << 17;

  float v0 = 0.f, v1 = 0.f; int kcur = -1;
  for (int i=0; i<256; ++i){
    int k = idxsh[i];
    if (k != kcur){
      if (kcur >= 0){
        acc[kcur*289 + f0] += v0;
        if (has1) acc[kcur*289 + f1] += v1;
      }
      v0 = 0.f; v1 = 0.f; kcur = k;
    }
    int h = (pc << 2) + (i >> 6), w_ = i & 63;
    int hh0 = h + dh0, ww0 = w_ + dw0;
    if ((unsigned)hh0 < 64u && (unsigned)ww0 < 64u)
      v0 += ld<BF>(x, xb + ((size_t)c0 << 12) + (hh0 << 6) + ww0);
    if (has1){
      int hh1 = h + dh1, ww1 = w_ + dw1;
      if ((unsigned)hh1 < 64u && (unsigned)ww1 < 64u)
        v1 += ld<BF>(x, xb + ((size_t)c1 << 12) + (hh1 << 6) + ww1);
    }
  }
  acc[kcur*289 + f0] += v0;
  if (has1) acc[kcur*289 + f1] += v1;
  __syncthreads();
  float* cp = cpart + (size_t)cg*(32*289);
  for (int e=t; e<32*289; e+=256){
    int r = e % 289;
    cp[e] = (r == 288) ? (float)icnt[e/289] : acc[e];
  }
}

__global__ __launch_bounds__(256) void kC(const void* x, const int* idxg,
                                          float* cpart, const int* flag){
  __shared__ float acc[32*289];
  __shared__ int   icnt[32];
  __shared__ int   idxsh[256];
  if (*flag) kC_body<true >(x, idxg, cpart, acc, icnt, idxsh);
  else       kC_body<false>(x, idxg, cpart, acc, icnt, idxsh);
}

// ---------------- Kernel D: merge partials -> centers + 2 MLPs + softmax (verified) --------
template<bool BF>
__device__ void kD_body(const float* __restrict__ cpart,
                        const void* kg_w1, const void* kg_b1,
                        const void* kg_w2, const void* kg_b2,
                        const void* kg_w3, const void* kg_b3,
                        const void* bg_w1, const void* bg_b1,
                        const void* bg_w2, const void* bg_b2,
                        const void* bg_w3, const void* bg_b3,
                        float* __restrict__ attn,
                        float* __restrict__ biasO,
                        float* __restrict__ row,
                        float* __restrict__ h1,
                        float* __restrict__ h2,
                        float* __restrict__ lgs){
  int wg = blockIdx.x; int b = wg >> 5; int k = wg & 31;
  int t = threadIdx.x;   // 64 threads
  float cnt = 0.f;
  for (int ch=0; ch<16; ++ch)
    cnt += cpart[((size_t)(b*16+ch)*32 + k)*289 + 288];
  float den = fmaxf(cnt, 1.f);
  for (int f=t; f<FF; f+=64){
    float s = 0.f;
    for (int ch=0; ch<16; ++ch)
      s += cpart[((size_t)(b*16+ch)*32 + k)*289 + f];
    row[f] = s / den;
  }
  __syncthreads();

  {
    float s = 0.f;
    #pragma unroll 8
    for (int f=0; f<FF; ++f) s = fmaf(row[f], ld<BF>(kg_w1, f*HID + t), s);
    h1[t] = fmaxf(s + ld<BF>(kg_b1, t), 0.f);
  }
  __syncthreads();
  {
    float s = 0.f;
    #pragma unroll 8
    for (int h=0; h<HID; ++h) s = fmaf(h1[h], ld<BF>(kg_w2, h*HID + t), s);
    h2[t] = fmaxf(s + ld<BF>(kg_b2, t), 0.f);
  }
  __syncthreads();
  if (t < 32){
    float s = 0.f;
    #pragma unroll 8
    for (int h=0; h<HID; ++h) s = fmaf(h2[h], ld<BF>(kg_w3, h*NBASE + t), s);
    lgs[t] = s + ld<BF>(kg_b3, t);
  }
  __syncthreads();
  if (t < 32){
    float mx = -3.0e38f;
    for (int i=0;i<NBASE;++i) mx = fmaxf(mx, lgs[i]);
    float se = 0.f;
    for (int i=0;i<NBASE;++i) se += expf(lgs[i]-mx);
    attn[wg*NBASE + t] = expf(lgs[t]-mx) / se;
  }
  __syncthreads();
  {
    float s = 0.f;
    #pragma unroll 8
    for (int f=0; f<FF; ++f) s = fmaf(row[f], ld<BF>(bg_w1, f*HID + t), s);
    h1[t] = fmaxf(s + ld<BF>(bg_b1, t), 0.f);
  }
  __syncthreads();
  {
    float s = 0.f;
    #pragma unroll 8
    for (int h=0; h<HID; ++h) s = fmaf(h1[h], ld<BF>(bg_w2, h*HID + t), s);
    h2[t] = fmaxf(s + ld<BF>(bg_b2, t), 0.f);
  }
  __syncthreads();
  {
    float s = 0.f;
    #pragma unroll 8
    for (int h=0; h<HID; ++h) s = fmaf(h2[h], ld<BF>(bg_w3, h*COUT + t), s);
    biasO[wg*COUT + t] = s + ld<BF>(bg_b3, t);
  }
}

__global__ __launch_bounds__(64) void kD(const float* cpart,
                                         const void* kg_w1, const void* kg_b1,
                                         const void* kg_w2, const void* kg_b2,
                                         const void* kg_w3, const void* kg_b3,
                                         const void* bg_w1, const void* bg_b1,
                                         const void* bg_w2, const void* bg_b2,
                                         const void* bg_w3, const void* bg_b3,
                                         float* attn, float* biasO, const int* flag){
  __shared__ float row[FF];
  __shared__ float h1[64];
  __shared__ float h2[64];
  __shared__ float lgs[32];
  if (*flag) kD_body<true >(cpart, kg_w1,kg_b1,kg_w2,kg_b2,kg_w3,kg_b3,
                            bg_w1,bg_b1,bg_w2,bg_b2,bg_w3,bg_b3, attn, biasO, row,h1,h2,lgs);
  else       kD_body<false>(cpart, kg_w1,kg_b1,kg_w2,kg_b2,kg_w3,kg_b3,
                            bg_w1,bg_b1,bg_w2,bg_b2,bg_w3,bg_b3, attn, biasO, row,h1,h2,lgs);
}

// ---------------- Kernel E: Wg[b][k][cout][f] (bf16) = sum_n attn*base (verified) ----------
template<bool BF>
__device__ void kE_body(const void* __restrict__ base,
                        const float* __restrict__ attn,
                        u16* __restrict__ Wg,
                        float* __restrict__ at,
                        float* __restrict__ tile){   // [72][65]
  int wg = blockIdx.x;
  int fq = wg & 3, bk = wg >> 2;
  int t = threadIdx.x;
  if (t < 32) at[t] = attn[bk*NBASE + t];
  __syncthreads();
  int f0 = fq*72;
  for (int e=t; e<72*64; e+=256){
    int fl = e >> 6, c = e & 63;
    size_t bi = (size_t)(f0 + fl)*COUT + c;
    float s = 0.f;
    #pragma unroll 8
    for (int n=0; n<NBASE; ++n)
      s = fmaf(at[n], ld<BF>(base, bi + (size_t)n*FF*COUT), s);
    tile[fl*65 + c] = s;
  }
  __syncthreads();
  for (int e=t; e<72*64; e+=256){
    int c = e / 72, fl = e % 72;
    Wg[(size_t)bk*(64*FF) + (size_t)c*FF + f0 + fl] = f2bf(tile[fl*65 + c]);
  }
}

__global__ __launch_bounds__(256) void kE(const void* base, const float* attn,
                                          u16* Wg, const int* flag){
  __shared__ float at[32];
  __shared__ float tile[72*65];
  if (*flag) kE_body<true >(base, attn, Wg, at, tile);
  else       kE_body<false>(base, attn, Wg, at, tile);
}

// ---------------- Kernel F: conv (R5 structure, verified) ----------------
template<bool BF>
__device__ void kF_body(const void* __restrict__ x,
                        const int* __restrict__ idxg,
                        const u16* __restrict__ Wg,
                        const float* __restrict__ biasO,
                        void* __restrict__ dout,
                        u16* __restrict__ patch,    // [16][296]
                        float* __restrict__ outT){  // [64][17]
  int wg = blockIdx.x;
  int q = wg & 3, h = (wg >> 2) & 63, b = wg >> 8;
  int t = threadIdx.x, wv = t >> 6, lane = t & 63;
  int w0 = q << 4;

  for (int e=t; e<16*FF; e+=256){
    int pl = e & 15, fe = e >> 4;
    int c = fe / 9, j = fe % 9;
    int hh = h + j/3 - 1, ww = w0 + pl + (j%3) - 1;
    float v = 0.f;
    if ((unsigned)hh < 64u && (unsigned)ww < 64u)
      v = ld<BF>(x, ((size_t)b << 17) + ((size_t)c << 12) + (hh<<6) + ww);
    patch[pl*296 + fe] = f2bf(v);
  }
  __syncthreads();

  #pragma unroll
  for (int i=0; i<4; ++i){
    int pl = (wv << 2) + i;
    int p = (h << 6) + w0 + pl;
    int k = idxg[(b << 12) + p];
    const uint4* Wp = (const uint4*)(Wg + ((size_t)((b << 5) + k)*64 + lane)*FF);
    const uint4* Pp = (const uint4*)(patch + pl*296);
    float acc = 0.f;
    #pragma unroll 6
    for (int j=0; j<36; ++j){
      uint4 wv4 = Wp[j];
      uint4 pv4 = Pp[j];
      acc = fmaf(u_lo(pv4.x), u_lo(wv4.x), acc);
      acc = fmaf(u_hi(pv4.x), u_hi(wv4.x), acc);
      acc = fmaf(u_lo(pv4.y), u_lo(wv4.y), acc);
      acc = fmaf(u_hi(pv4.y), u_hi(wv4.y), acc);
      acc = fmaf(u_lo(pv4.z), u_lo(wv4.z), acc);
      acc = fmaf(u_hi(pv4.z), u_hi(wv4.z), acc);
      acc = fmaf(u_lo(pv4.w), u_lo(wv4.w), acc);
      acc = fmaf(u_hi(pv4.w), u_hi(wv4.w), acc);
    }
    float bias = biasO[((b << 5) + k)*COUT + lane];
    outT[lane*17 + pl] = acc + bias;
  }
  __syncthreads();

  for (int e=t; e<1024; e+=256){
    int cout = e >> 4, pl = e & 15;
    st<BF>(dout, (((size_t)(b << 6) + cout) << 12) + (h << 6) + w0 + pl,
           outT[cout*17 + pl]);
  }
}

__global__ __launch_bounds__(256) void kF(const void* x, const int* idxg,
                                          const u16* Wg, const float* biasO,
                                          void* dout, const int* flag){
  __shared__ u16   patch[16*296];
  __shared__ float outT[64*17];
  if (*flag) kF_body<true >(x, idxg, Wg, biasO, dout, patch, outT);
  else       kF_body<false>(x, idxg, Wg, biasO, dout, patch, outT);
}

// ---------------- host: JAX threefry2x32 + permutation(key,4096)[:32] ----------------
static inline uint32_t rotl32(uint32_t x, int d){ return (x<<d)|(x>>(32-d)); }
static void tf_block(uint32_t k0,uint32_t k1,uint32_t x0,uint32_t x1,uint32_t&o0,uint32_t&o1){
  uint32_t ks2 = k0 ^ k1 ^ 0x1BD11BDAu;
  uint32_t v0 = x0 + k0, v1 = x1 + k1;
  const int ra[4]={13,15,26,6}, rb[4]={17,29,16,24};
  #define R4(r) for(int i_=0;i_<4;++i_){ v0 += v1; v1 = rotl32(v1,(r)[i_]); v1 ^= v0; }
  R4(ra); v0 += k1;  v1 += ks2 + 1u;
  R4(rb); v0 += ks2; v1 += k0  + 2u;
  R4(ra); v0 += k0;  v1 += k1  + 3u;
  R4(rb); v0 += k1;  v1 += ks2 + 4u;
  R4(ra); v0 += ks2; v1 += k0  + 5u;
  #undef R4
  o0 = v0; o1 = v1;
}
struct KP{ uint32_t a, b; };
static void tf_split(KP k, KP& first, KP& second){
#if THREEFRY_PARTITIONABLE
  uint32_t a0,b0,a1,b1;
  tf_block(k.a,k.b, 0u,0u, a0,b0);
  tf_block(k.a,k.b, 0u,1u, a1,b1);
  first  = KP{a0,b0};
  second = KP{a1,b1};
#else
  uint32_t a0,b0,a1,b1;
  tf_block(k.a,k.b, 0u,2u, a0,b0);
  tf_block(k.a,k.b, 1u,3u, a1,b1);
  first  = KP{a0,a1};
  second = KP{b0,b1};
#endif
}
static void random_bits_4096(KP k, std::vector<uint32_t>& bits){
#if THREEFRY_PARTITIONABLE
  for (int i=0;i<4096;++i){
    uint32_t o0,o1; tf_block(k.a,k.b, 0u,(uint32_t)i, o0,o1);
    bits[i] = o0 ^ o1;
  }
#else
  for (int i=0;i<2048;++i){
    uint32_t o0,o1; tf_block(k.a,k.b,(uint32_t)i,(uint32_t)(i+2048),o0,o1);
    bits[i] = o0; bits[i+2048] = o1;
  }
#endif
}
static void perm_first32(KP key, int* out32){
  std::vector<int> vals(4096);
  for (int i=0;i<4096;++i) vals[i] = i;
  std::vector<uint32_t> bits(4096);
  std::vector<std::pair<uint32_t,int>> pr(4096);
  KP k = key;
  for (int r=0;r<2;++r){
    KP nk, sk; tf_split(k, nk, sk); k = nk;
    random_bits_4096(sk, bits);
    for (int i=0;i<4096;++i) pr[i] = std::make_pair(bits[i], vals[i]);
    std::stable_sort(pr.begin(), pr.end(),
        [](const std::pair<uint32_t,int>& a, const std::pair<uint32_t,int>& c){ return a.first < c.first; });
    for (int i=0;i<4096;++i) vals[i] = pr[i].second;
  }
  for (int j=0;j<32;++j) out32[j] = vals[j];
}

extern "C" void kernel_launch(void* const* d_in, const int* in_sizes, int n_in,
                              void* d_out, int out_size, void* d_ws, size_t ws_size,
                              hipStream_t stream) {
  const void* x     = d_in[0];
  const void* base  = d_in[1];
  const void* kg_w1 = d_in[2];
  const void* kg_b1 = d_in[3];
  const void* kg_w2 = d_in[4];
  const void* kg_b2 = d_in[5];
  const void* kg_w3 = d_in[6];
  const void* kg_b3 = d_in[7];
  const void* bg_w1 = d_in[8];
  const void* bg_b1 = d_in[9];
  const void* bg_w2 = d_in[10];
  const void* bg_b2 = d_in[11];
  const void* bg_w3 = d_in[12];
  const void* bg_b3 = d_in[13];

  char* ws = (char*)d_ws;
  int*   flag  = (int*)(ws + 64);
  int*   idxg  = (int*)(ws + OFF_IDX);
  float* attn  = (float*)(ws + OFF_ATTN);
  float* biasO = (float*)(ws + OFF_BIAS);
  float* part  = (float*)(ws + OFF_PART);
  float* cnts  = (float*)(ws + OFF_CNTS);
  float* cpart = (float*)(ws + OFF_CPART);
  u16*   Wg    = (u16*)(ws + OFF_WG);
  int*   slots = (int*)(ws + OFF_BAR2);
  int*   gen   = (int*)(ws + OFF_BAR2 + 2048);

  InitIdx ii;
  KP root = KP{0u, 42u};
  KP kb0, kb1; tf_split(root, kb0, kb1);
  perm_first32(kb0, ii.v[0]);
  perm_first32(kb1, ii.v[1]);

  hipMemsetAsync(ws + OFF_BAR2, 0, 4096, stream);   // barrier slots + gen

  kDetect<<<1, 256, 0, stream>>>(x, flag);
  kB<<<NWG_KM, 256, 0, stream>>>(x, part, cnts, idxg, d_out, slots, gen, flag, ii);
  kC<<<32, 256, 0, stream>>>(x, idxg, cpart, flag);
  kD<<<64, 64, 0, stream>>>(cpart,
                            kg_w1, kg_b1, kg_w2, kg_b2, kg_w3, kg_b3,
                            bg_w1, bg_b1, bg_w2, bg_b2, bg_w3, bg_b3,
                            attn, biasO, flag);
  kE<<<256, 256, 0, stream>>>(base, attn, Wg, flag);
  kF<<<512, 256, 0, stream>>>(x, idxg, Wg, biasO, d_out, flag);
}